// Round 1
// baseline (356.098 us; speedup 1.0000x reference)
//
#include <hip/hip_runtime.h>

#define PHI 720
#define TS 1024
#define NBATCH 16
#define NPIX 256

// ---------------------------------------------------------------------------
// Kernel 1: per-row circular filtering: row <- irfft(K * rfft(row)).
// Phase/DT factors of the reference cancel exactly (conj(phase)*phase == 1).
// Two real rows are packed as one complex sequence; since the Hermitian
// multiplier acts identically on both spectra, W = K_full .* FFT(r0 + i r1)
// and IFFT(W) yields filtered rows in Re/Im parts directly.
// In-place over the sinogram buffer (harness restores inputs every launch).
// Stockham radix-2, 10 fwd + 10 inv stages, ping-pong in LDS.
// ---------------------------------------------------------------------------
__device__ __forceinline__ float2 cmulf2(float2 a, float2 b) {
    return make_float2(a.x * b.x - a.y * b.y, a.x * b.y + a.y * b.x);
}

__global__ __launch_bounds__(256) void filter_fft_kernel(float* __restrict__ sinos,
                                                         const float* __restrict__ kr,
                                                         const float* __restrict__ ki) {
    __shared__ float2 bufA[TS];
    __shared__ float2 bufB[TS];
    __shared__ float2 tw[TS / 2];

    const int tid = threadIdx.x;
    float* row0 = sinos + (size_t)blockIdx.x * (2 * TS);
    float* row1 = row0 + TS;

    #pragma unroll
    for (int h = 0; h < 4; ++h) {
        const int k = tid + h * 256;
        bufA[k] = make_float2(row0[k], row1[k]);
    }
    #pragma unroll
    for (int h = 0; h < 2; ++h) {
        const int k = tid + h * 256;
        const float ang = (float)k * (6.28318530717958647692f / (float)TS);
        float s, c;
        sincosf(ang, &s, &c);
        tw[k] = make_float2(c, -s);       // exp(-2*pi*i*k/N)
    }
    __syncthreads();

    float2* src = bufA;
    float2* dst = bufB;

    // forward FFT
    #pragma unroll
    for (int st = 0; st < 10; ++st) {
        const int m = 1 << st;
        #pragma unroll
        for (int h = 0; h < 2; ++h) {
            const int idx = tid + h * 256;
            const int q = idx & ~(m - 1);
            const float2 a = src[idx];
            const float2 b = src[idx + 512];
            const float2 w = tw[q];
            const float2 d = make_float2(a.x - b.x, a.y - b.y);
            dst[idx + q]     = make_float2(a.x + b.x, a.y + b.y);
            dst[idx + q + m] = cmulf2(w, d);
        }
        __syncthreads();
        float2* t = src; src = dst; dst = t;
    }

    // pointwise multiply by Hermitian-extended kernel (imag dropped at DC and
    // Nyquist, matching irfft semantics), folding in the 1/N IFFT scale.
    const float scale = 1.0f / (float)TS;
    #pragma unroll
    for (int h = 0; h < 4; ++h) {
        const int k = tid + h * 256;
        const int kk = (k <= 512) ? k : (TS - k);
        const float re = kr[kk] * scale;
        float im = ((k == 0) || (k == 512)) ? 0.0f : ki[kk] * scale;
        if (k > 512) im = -im;
        const float2 z = src[k];
        src[k] = make_float2(re * z.x - im * z.y, re * z.y + im * z.x);
    }
    __syncthreads();

    // inverse FFT (conjugated twiddles)
    #pragma unroll
    for (int st = 0; st < 10; ++st) {
        const int m = 1 << st;
        #pragma unroll
        for (int h = 0; h < 2; ++h) {
            const int idx = tid + h * 256;
            const int q = idx & ~(m - 1);
            const float2 a = src[idx];
            const float2 b = src[idx + 512];
            float2 w = tw[q];
            w.y = -w.y;
            const float2 d = make_float2(a.x - b.x, a.y - b.y);
            dst[idx + q]     = make_float2(a.x + b.x, a.y + b.y);
            dst[idx + q + m] = cmulf2(w, d);
        }
        __syncthreads();
        float2* t = src; src = dst; dst = t;
    }

    #pragma unroll
    for (int h = 0; h < 4; ++h) {
        const int k = tid + h * 256;
        const float2 v = src[k];
        row0[k] = v.x;   // filtered even row
        row1[k] = v.y;   // filtered odd row
    }
}

// ---------------------------------------------------------------------------
// Kernel 2: backprojection. One block = (batch b, 32x32 pixel tile).
// 256 threads: lane = j within tile (fast/output axis), r = tid>>5 selects a
// 4-row strip in i; each thread accumulates 4 pixels.
// Per 8-angle chunk: stage each angle's 128-bin detector window into LDS
// (tile u-span <= 124 bins + guards), then lerp from LDS.
// u = t * (1/DT) + (RHO/DT - 0.5) = t*362.0386... + 511.5 exactly.
// ---------------------------------------------------------------------------
__global__ __launch_bounds__(256) void backproj_kernel(const float* __restrict__ filt,
                                                       float* __restrict__ out) {
    __shared__ float2 csTab[PHI];
    __shared__ float win[8 * 128];
    __shared__ int woffs[8];

    const int tid = threadIdx.x;
    // XCD-aware swizzle: 1024 blocks -> each XCD gets 128 consecutive logical
    // blocks = 2 full batches (2 x 2.95MB filtered slices, L2-friendly).
    const int wg = blockIdx.x;
    const int lb = ((wg & 7) << 7) | (wg >> 3);
    const int b = lb >> 6;
    const int tile = lb & 63;
    const int i0 = (tile >> 3) * 32;
    const int j0 = (tile & 7) * 32;

    for (int p = tid; p < PHI; p += 256) {
        const float ang = ((float)p + 0.5f) * (float)(3.14159265358979323846 / 720.0);
        float s, c;
        sincosf(ang, &s, &c);
        csTab[p] = make_float2(c, s);
    }

    const int lane = tid & 31;
    const int r = tid >> 5;
    const int j = j0 + lane;
    const int ib = i0 + r * 4;

    const float DX = 2.0f / 256.0f;
    const float Yc = -1.0f + ((float)j + 0.5f) * DX;
    const float X0 = -1.0f + ((float)ib + 0.5f) * DX;
    const float xlo = -1.0f + ((float)i0 + 0.5f) * DX;
    const float xhi = -1.0f + ((float)i0 + 31.5f) * DX;
    const float ylo = -1.0f + ((float)j0 + 0.5f) * DX;
    const float yhi = -1.0f + ((float)j0 + 31.5f) * DX;
    const float INVDT = 362.03867196751236f;   // 1024 / (2*sqrt(2))
    const float UOFF = 511.5f;                 // RHO/DT - 0.5

    const float* gb = filt + (size_t)b * PHI * TS;
    const float* w0 = win;
    float acc[4] = {0.0f, 0.0f, 0.0f, 0.0f};

    __syncthreads();   // csTab ready

    for (int chunk = 0; chunk < PHI / 8; ++chunk) {
        // ---- stage: angle slot r (all 32 lanes cooperate) ----
        const int angS = chunk * 8 + r;
        const float2 cs = csTab[angS];
        const float tmin = fminf(cs.x * xlo, cs.x * xhi) + fminf(cs.y * ylo, cs.y * yhi);
        const int wb = (int)floorf(fmaf(tmin, INVDT, UOFF)) - 1;
        const float* grow = gb + (size_t)angS * TS;
        #pragma unroll
        for (int h = 0; h < 4; ++h) {
            const int k = lane + h * 32;
            int gi = wb + k;
            gi = gi < 0 ? 0 : (gi > TS - 1 ? TS - 1 : gi);  // OOB entries never read
            win[r * 128 + k] = grow[gi];
        }
        if (lane == 0) woffs[r] = r * 128 - wb;
        __syncthreads();

        // ---- accumulate 8 angles x 4 pixels ----
        #pragma unroll
        for (int aa = 0; aa < 8; ++aa) {
            const float2 c2 = csTab[chunk * 8 + aa];
            const int off = woffs[aa];
            float u = fmaf(fmaf(c2.x, X0, c2.y * Yc), INVDT, UOFF);
            const float du = c2.x * 2.8284271247461903f;  // dx/DT per i-step
            #pragma unroll
            for (int p = 0; p < 4; ++p) {
                float fl = floorf(u);
                fl = fminf(fmaxf(fl, 0.0f), 1022.0f);
                const int idx = (int)fl + off;            // always in [aa*128, aa*128+127]
                const float wf = u - fl;                  // may exceed [0,1] at edges (matches ref)
                const float g0 = w0[idx];
                const float g1 = w0[idx + 1];
                acc[p] = fmaf(wf, g1 - g0, acc[p] + g0);
                u += du;
            }
        }
        __syncthreads();
    }

    const float DPHI_F = (float)(3.14159265358979323846 / 720.0);
    const size_t ob = ((size_t)b * NPIX + ib) * NPIX + j;
    out[ob]            = acc[0] * DPHI_F;
    out[ob + NPIX]     = acc[1] * DPHI_F;
    out[ob + 2 * NPIX] = acc[2] * DPHI_F;
    out[ob + 3 * NPIX] = acc[3] * DPHI_F;
}

extern "C" void kernel_launch(void* const* d_in, const int* in_sizes, int n_in,
                              void* d_out, int out_size, void* d_ws, size_t ws_size,
                              hipStream_t stream) {
    float* sinos = (float*)d_in[0];          // [16,720,1024] f32, filtered in-place
    const float* kr = (const float*)d_in[1]; // [513]
    const float* ki = (const float*)d_in[2]; // [513]
    float* out = (float*)d_out;              // [16,256,256] f32

    filter_fft_kernel<<<NBATCH * PHI / 2, 256, 0, stream>>>(sinos, kr, ki);
    backproj_kernel<<<NBATCH * 64, 256, 0, stream>>>(sinos, out);
}

// Round 2
// 336.748 us; speedup vs baseline: 1.0575x; 1.0575x over previous
//
#include <hip/hip_runtime.h>

#define PHI 720
#define TS 1024
#define NBATCH 16
#define NPIX 256

#define INVDT 362.03867196751236f            // 1024 / (2*sqrt(2))
#define DXF   (2.0f / 256.0f)
#define DPHI_F 0.0043633231299858237f        // pi/720
#define WS_NEEDED ((TS / 2 + PHI) * sizeof(float2))

__device__ __forceinline__ float2 cmulf2(float2 a, float2 b) {
    return make_float2(a.x * b.x - a.y * b.y, a.x * b.y + a.y * b.x);
}

__device__ __forceinline__ float fractf_fast(float x) {
#if __has_builtin(__builtin_amdgcn_fractf)
    return __builtin_amdgcn_fractf(x);
#else
    return x - floorf(x);
#endif
}

// ---------------------------------------------------------------------------
// Kernel 0: trig tables into d_ws (recomputed every launch; graph-safe).
// ws[0..511]   = exp(-2*pi*i*k/1024)   (FFT twiddles)
// ws[512..1231]= (cos, sin) of backprojection angles
// ---------------------------------------------------------------------------
__global__ __launch_bounds__(256) void precompute_kernel(float2* __restrict__ ws) {
    const int t = blockIdx.x * 256 + threadIdx.x;
    if (t < TS / 2) {
        const float ang = (float)t * (6.28318530717958647692f / (float)TS);
        float s, c;
        sincosf(ang, &s, &c);
        ws[t] = make_float2(c, -s);
    } else if (t < TS / 2 + PHI) {
        const int p = t - TS / 2;
        const float ang = ((float)p + 0.5f) * (float)(3.14159265358979323846 / 720.0);
        float s, c;
        sincosf(ang, &s, &c);
        ws[t] = make_float2(c, s);
    }
}

// ---------------------------------------------------------------------------
// Kernel 1: per-row circular filtering: row <- irfft(K * rfft(row)) * DPHI.
// Phase/DT factors of the reference cancel exactly. Two real rows packed as
// one complex FFT (Hermitian multiplier => Re/Im separate exactly).
// Stockham radix-2, in-place over the sinogram buffer.
// ---------------------------------------------------------------------------
__global__ __launch_bounds__(256) void filter_fft_kernel(float* __restrict__ sinos,
                                                         const float* __restrict__ kr,
                                                         const float* __restrict__ ki,
                                                         const float2* __restrict__ twg) {
    __shared__ float2 bufA[TS];
    __shared__ float2 bufB[TS];
    __shared__ float2 tw[TS / 2];

    const int tid = threadIdx.x;
    float* row0 = sinos + (size_t)blockIdx.x * (2 * TS);
    float* row1 = row0 + TS;

    #pragma unroll
    for (int h = 0; h < 4; ++h) {
        const int k = tid + h * 256;
        bufA[k] = make_float2(row0[k], row1[k]);
    }
    if (twg) {
        tw[tid] = twg[tid];
        tw[tid + 256] = twg[tid + 256];
    } else {
        #pragma unroll
        for (int h = 0; h < 2; ++h) {
            const int k = tid + h * 256;
            const float ang = (float)k * (6.28318530717958647692f / (float)TS);
            float s, c;
            sincosf(ang, &s, &c);
            tw[k] = make_float2(c, -s);
        }
    }
    __syncthreads();

    float2* src = bufA;
    float2* dst = bufB;

    // forward FFT
    #pragma unroll
    for (int st = 0; st < 10; ++st) {
        const int m = 1 << st;
        #pragma unroll
        for (int h = 0; h < 2; ++h) {
            const int idx = tid + h * 256;
            const int q = idx & ~(m - 1);
            const float2 a = src[idx];
            const float2 b = src[idx + 512];
            const float2 w = tw[q];
            const float2 d = make_float2(a.x - b.x, a.y - b.y);
            dst[idx + q]     = make_float2(a.x + b.x, a.y + b.y);
            dst[idx + q + m] = cmulf2(w, d);
        }
        __syncthreads();
        float2* t = src; src = dst; dst = t;
    }

    // pointwise multiply by Hermitian-extended kernel; fold 1/N and DPHI.
    const float scale = DPHI_F / (float)TS;
    #pragma unroll
    for (int h = 0; h < 4; ++h) {
        const int k = tid + h * 256;
        const int kk = (k <= 512) ? k : (TS - k);
        const float re = kr[kk] * scale;
        float im = ((k == 0) || (k == 512)) ? 0.0f : ki[kk] * scale;
        if (k > 512) im = -im;
        const float2 z = src[k];
        src[k] = make_float2(re * z.x - im * z.y, re * z.y + im * z.x);
    }
    __syncthreads();

    // inverse FFT (conjugated twiddles)
    #pragma unroll
    for (int st = 0; st < 10; ++st) {
        const int m = 1 << st;
        #pragma unroll
        for (int h = 0; h < 2; ++h) {
            const int idx = tid + h * 256;
            const int q = idx & ~(m - 1);
            const float2 a = src[idx];
            const float2 b = src[idx + 512];
            float2 w = tw[q];
            w.y = -w.y;
            const float2 d = make_float2(a.x - b.x, a.y - b.y);
            dst[idx + q]     = make_float2(a.x + b.x, a.y + b.y);
            dst[idx + q + m] = cmulf2(w, d);
        }
        __syncthreads();
        float2* t = src; src = dst; dst = t;
    }

    #pragma unroll
    for (int h = 0; h < 4; ++h) {
        const int k = tid + h * 256;
        const float2 v = src[k];
        row0[k] = v.x;
        row1[k] = v.y;
    }
}

// ---------------------------------------------------------------------------
// Kernel 2: backprojection. One block = (batch b, 32x32 pixel tile).
// Each wave covers an 8-wide j-strip; its 64 lanes form an 8(i) x 8(j) patch,
// replicated at 4 i-offsets (ii + 8p). Patch address span per angle is
// 7*2.8284*(|c|+|s|) <= 28 dwords < 32 banks => conflict-free ds_read2.
// Per 8-angle chunk the 128-bin detector windows are staged to LDS with
// register prefetch (global loads issued before the compute phase).
// Window offset + 511.5 folded into a float so the inner lerp is:
// cvt_i32, v_fract, ds_read2, sub, add, fma, add.
// ---------------------------------------------------------------------------
__global__ __launch_bounds__(256) void backproj_kernel(const float* __restrict__ filt,
                                                       float* __restrict__ out,
                                                       const float2* __restrict__ csg) {
    __shared__ float2 csI[PHI];      // (cos, sin) * INVDT
    __shared__ float win[8 * 128];
    __shared__ float woffF[8];

    const int tid = threadIdx.x;
    // XCD-aware swizzle: each XCD gets 128 consecutive logical blocks = 2 batches.
    const int wg = blockIdx.x;
    const int lb = ((wg & 7) << 7) | (wg >> 3);
    const int b = lb >> 6;
    const int tile = lb & 63;
    const int i0 = (tile >> 3) * 32;
    const int j0 = (tile & 7) * 32;

    if (csg) {
        for (int p = tid; p < PHI; p += 256) {
            const float2 g = csg[TS / 2 + p];
            csI[p] = make_float2(g.x * INVDT, g.y * INVDT);
        }
    } else {
        for (int p = tid; p < PHI; p += 256) {
            const float ang = ((float)p + 0.5f) * (float)(3.14159265358979323846 / 720.0);
            float s, c;
            sincosf(ang, &s, &c);
            csI[p] = make_float2(c * INVDT, s * INVDT);
        }
    }

    const int lane = tid & 63;
    const int wv = tid >> 6;         // wave 0..3 -> j-strip
    const int ii = lane & 7;         // i within patch
    const int jj = lane >> 3;        // j within patch
    const int ip = i0 + ii;          // pixel i = ip + 8p
    const int j  = j0 + wv * 8 + jj;

    const float Xc = -1.0f + ((float)ip + 0.5f) * DXF;
    const float Yc = -1.0f + ((float)j + 0.5f) * DXF;

    const int r = tid >> 5;          // staging slot 0..7 (half-wave)
    const int l32 = tid & 31;
    const float xlo = -1.0f + ((float)i0 + 0.5f) * DXF;
    const float xhi = -1.0f + ((float)i0 + 31.5f) * DXF;
    const float ylo = -1.0f + ((float)j0 + 0.5f) * DXF;
    const float yhi = -1.0f + ((float)j0 + 31.5f) * DXF;

    const float* gb = filt + (size_t)b * PHI * TS;
    float acc0 = 0.0f, acc1 = 0.0f, acc2 = 0.0f, acc3 = 0.0f;

    __syncthreads();                 // csI ready

    // prologue: stage chunk 0 directly
    {
        const float2 cs = csI[r];
        const float um = fminf(cs.x * xlo, cs.x * xhi) + fminf(cs.y * ylo, cs.y * yhi) + 511.5f;
        const int wb = (int)floorf(um) - 1;
        const float* grow = gb + (size_t)r * TS;
        #pragma unroll
        for (int h = 0; h < 4; ++h) {
            int gi = wb + l32 + 32 * h;
            gi = gi < 0 ? 0 : (gi > TS - 1 ? TS - 1 : gi);   // OOB never read
            win[r * 128 + l32 + 32 * h] = grow[gi];
        }
        if (l32 == 0) woffF[r] = 511.5f + (float)(r * 128 - wb);
    }
    __syncthreads();

    for (int c = 0; c < PHI / 8; ++c) {
        // ---- issue next chunk's staging loads into registers ----
        float gp0 = 0.f, gp1 = 0.f, gp2 = 0.f, gp3 = 0.f;
        int wbn = 0;
        const bool more = (c + 1 < PHI / 8);
        if (more) {
            const int a = (c + 1) * 8 + r;
            const float2 cs = csI[a];
            const float um = fminf(cs.x * xlo, cs.x * xhi) + fminf(cs.y * ylo, cs.y * yhi) + 511.5f;
            wbn = (int)floorf(um) - 1;
            const float* grow = gb + (size_t)a * TS;
            int g0 = wbn + l32;       g0 = g0 < 0 ? 0 : (g0 > TS - 1 ? TS - 1 : g0);
            int g1 = wbn + l32 + 32;  g1 = g1 < 0 ? 0 : (g1 > TS - 1 ? TS - 1 : g1);
            int g2 = wbn + l32 + 64;  g2 = g2 < 0 ? 0 : (g2 > TS - 1 ? TS - 1 : g2);
            int g3 = wbn + l32 + 96;  g3 = g3 < 0 ? 0 : (g3 > TS - 1 ? TS - 1 : g3);
            gp0 = grow[g0]; gp1 = grow[g1]; gp2 = grow[g2]; gp3 = grow[g3];
        }

        // ---- accumulate 8 angles x 4 patches from LDS ----
        #pragma unroll
        for (int aa = 0; aa < 8; ++aa) {
            const float2 cs = csI[c * 8 + aa];
            const float offF = woffF[aa];
            float u = fmaf(cs.y, Yc, cs.x * Xc) + offF;   // in [aa*128+1, aa*128+126]
            const float dup = cs.x * 0.0625f;             // 8 i-steps in index units
            {
                const int idx = (int)u;
                const float wf = fractf_fast(u);
                const float g0 = win[idx], g1 = win[idx + 1];
                acc0 = fmaf(wf, g1 - g0, acc0 + g0);
                u += dup;
            }
            {
                const int idx = (int)u;
                const float wf = fractf_fast(u);
                const float g0 = win[idx], g1 = win[idx + 1];
                acc1 = fmaf(wf, g1 - g0, acc1 + g0);
                u += dup;
            }
            {
                const int idx = (int)u;
                const float wf = fractf_fast(u);
                const float g0 = win[idx], g1 = win[idx + 1];
                acc2 = fmaf(wf, g1 - g0, acc2 + g0);
                u += dup;
            }
            {
                const int idx = (int)u;
                const float wf = fractf_fast(u);
                const float g0 = win[idx], g1 = win[idx + 1];
                acc3 = fmaf(wf, g1 - g0, acc3 + g0);
            }
        }
        __syncthreads();             // everyone done reading win
        if (more) {
            win[r * 128 + l32]      = gp0;
            win[r * 128 + l32 + 32] = gp1;
            win[r * 128 + l32 + 64] = gp2;
            win[r * 128 + l32 + 96] = gp3;
            if (l32 == 0) woffF[r] = 511.5f + (float)(r * 128 - wbn);
        }
        __syncthreads();             // win ready for next chunk
    }

    // DPHI already folded into the filter scale.
    const size_t ob = ((size_t)b * NPIX + ip) * NPIX + j;
    out[ob]             = acc0;
    out[ob + 8 * NPIX]  = acc1;
    out[ob + 16 * NPIX] = acc2;
    out[ob + 24 * NPIX] = acc3;
}

extern "C" void kernel_launch(void* const* d_in, const int* in_sizes, int n_in,
                              void* d_out, int out_size, void* d_ws, size_t ws_size,
                              hipStream_t stream) {
    float* sinos = (float*)d_in[0];          // [16,720,1024] f32, filtered in-place
    const float* kr = (const float*)d_in[1]; // [513]
    const float* ki = (const float*)d_in[2]; // [513]
    float* out = (float*)d_out;              // [16,256,256] f32

    float2* tab = nullptr;
    if (ws_size >= WS_NEEDED && d_ws != nullptr) {
        tab = (float2*)d_ws;
        precompute_kernel<<<(TS / 2 + PHI + 255) / 256, 256, 0, stream>>>(tab);
    }
    filter_fft_kernel<<<NBATCH * PHI / 2, 256, 0, stream>>>(sinos, kr, ki, tab);
    backproj_kernel<<<NBATCH * 64, 256, 0, stream>>>(sinos, out, tab);
}

// Round 3
// 315.456 us; speedup vs baseline: 1.1288x; 1.0675x over previous
//
#include <hip/hip_runtime.h>

#define PHI 720
#define TS 1024
#define NB 16
#define NPIX 256

#define INVDT 362.03867196751236f      // 1024 / (2*sqrt(2))
#define DXF 0.0078125f                 // 2/256
#define DPHI_F 0.0043633231299858237f  // pi/720

// d_ws layout (bytes):
//   WS_TW : float2 tw[512]      FFT twiddles exp(-2pi i k/1024)
//   WS_ANG: float4 ang[720]     (cos*INVDT, sin*INVDT, cos*INVDT/16, 0)
//   WS_KW : int2 [64][720]      (.x = bits of float(511.5 - wb), .y = wb)
#define WS_TW 0
#define WS_ANG 4096
#define WS_KW 15616
#define WS_NEEDED 384256

__device__ __forceinline__ float2 cmulf2(float2 a, float2 b) {
    return make_float2(a.x * b.x - a.y * b.y, a.x * b.y + a.y * b.x);
}
__device__ __forceinline__ float fract_fast(float x) {
#if __has_builtin(__builtin_amdgcn_fractf)
    return __builtin_amdgcn_fractf(x);
#else
    return x - floorf(x);
#endif
}

// ---------------------------------------------------------------------------
// Kernel 0: tables into d_ws (recomputed every launch; graph-safe).
// ---------------------------------------------------------------------------
__global__ __launch_bounds__(256) void precompute_kernel(char* __restrict__ wsb) {
    const int t = blockIdx.x * 256 + threadIdx.x;
    if (t < 512) {
        float s, c;
        sincosf((float)t * (6.28318530717958647692f / 1024.0f), &s, &c);
        ((float2*)(wsb + WS_TW))[t] = make_float2(c, -s);
    } else if (t < 512 + PHI) {
        const int p = t - 512;
        float s, c;
        sincosf(((float)p + 0.5f) * (3.14159265358979323846f / 720.0f), &s, &c);
        ((float4*)(wsb + WS_ANG))[p] =
            make_float4(c * INVDT, s * INVDT, c * INVDT * 0.0625f, 0.0f);
    } else if (t < 512 + PHI + 64 * PHI) {
        const int e = t - 512 - PHI;
        const int st = e / PHI;          // supertile 0..63  (ist*8 + jst4)
        const int p = e - st * PHI;
        float s, c;
        sincosf(((float)p + 0.5f) * (3.14159265358979323846f / 720.0f), &s, &c);
        const float cx = c * INVDT, cy = s * INVDT;
        const int i0 = (st >> 3) * 32, j0 = (st & 7) * 32;
        const float x0 = -1.0f + ((float)i0 + 0.5f) * DXF;
        const float x1 = x0 + 31.0f * DXF;
        const float y0 = -1.0f + ((float)j0 + 0.5f) * DXF;
        const float y1 = y0 + 31.0f * DXF;
        // supertile u-span <= 124 bins; wb chosen so local u in (0,127) strictly
        const float umin = fminf(cx * x0, cx * x1) + fminf(cy * y0, cy * y1) + 511.5f;
        int wb = (int)floorf(umin - 0.01f) - 1;
        wb = wb < 0 ? 0 : (wb > TS - 128 ? TS - 128 : wb);
        ((int2*)(wsb + WS_KW))[e] = make_int2(__float_as_int(511.5f - (float)wb), wb);
    }
}

// ---------------------------------------------------------------------------
// Kernel 1: circular filtering row <- irfft(K * rfft(row)) * DPHI.
// Radix-4 Stockham (two radix-2 stages fused in registers; derived from the
// verified radix-2 indexing), 5 fwd + 5 inv stages, 2 packed FFTs per block
// (4 sino rows), ping-pong LDS. Phase/DT factors of the reference cancel.
// ---------------------------------------------------------------------------
__device__ __forceinline__ void r4_stage(const float2* __restrict__ s0, float2* __restrict__ d0,
                                         const float2* __restrict__ s1, float2* __restrict__ d1,
                                         const float2* __restrict__ tw, int tid, int m, bool inv) {
    const int q = tid & ~(m - 1);
    const int o = tid + 3 * q;          // 4*q + (tid - q)
    float2 w1 = tw[q], w2 = tw[2 * q];
    if (inv) { w1.y = -w1.y; w2.y = -w2.y; }
    #pragma unroll
    for (int f = 0; f < 2; ++f) {
        const float2* s = f ? s1 : s0;
        float2* d = f ? d1 : d0;
        const float2 a = s[tid], b = s[tid + 256], c = s[tid + 512], e = s[tid + 768];
        const float2 A = make_float2(a.x + c.x, a.y + c.y);
        const float2 Bm = cmulf2(w1, make_float2(a.x - c.x, a.y - c.y));
        const float2 C = make_float2(b.x + e.x, b.y + e.y);
        const float2 Dm = cmulf2(w1, make_float2(b.x - e.x, b.y - e.y));
        const float2 D = inv ? make_float2(-Dm.y, Dm.x) : make_float2(Dm.y, -Dm.x);
        d[o]         = make_float2(A.x + C.x, A.y + C.y);
        d[o + m]     = make_float2(Bm.x + D.x, Bm.y + D.y);
        d[o + 2 * m] = cmulf2(w2, make_float2(A.x - C.x, A.y - C.y));
        d[o + 3 * m] = cmulf2(w2, make_float2(Bm.x - D.x, Bm.y - D.y));
    }
}

__global__ __launch_bounds__(256) void filter_fft_kernel(float* __restrict__ sinos,
                                                         const float* __restrict__ kr,
                                                         const float* __restrict__ ki,
                                                         const char* __restrict__ wsb) {
    __shared__ float2 bufA[2][1024];
    __shared__ float2 bufB[2][1024];
    __shared__ float2 tw[512];
    const int tid = threadIdx.x;
    // XCD swizzle: 2880 blocks -> each XCD owns 360 consecutive logical blocks
    // = 2 batches, matching the backprojection batch->XCD mapping.
    const int wg = blockIdx.x;
    const int lb = (wg & 7) * 360 + (wg >> 3);
    float* base = sinos + (size_t)lb * 4096;

    #pragma unroll
    for (int f = 0; f < 2; ++f) {
        float* r0 = base + f * 2048;
        float* r1 = r0 + 1024;
        #pragma unroll
        for (int h = 0; h < 4; ++h) {
            const int k = tid + h * 256;
            bufA[f][k] = make_float2(r0[k], r1[k]);
        }
    }
    if (wsb) {
        const float2* tg = (const float2*)(wsb + WS_TW);
        tw[tid] = tg[tid];
        tw[tid + 256] = tg[tid + 256];
    } else {
        #pragma unroll
        for (int h = 0; h < 2; ++h) {
            const int k = tid + h * 256;
            float s, c;
            sincosf((float)k * (6.28318530717958647692f / 1024.0f), &s, &c);
            tw[k] = make_float2(c, -s);
        }
    }
    __syncthreads();

    r4_stage(bufA[0], bufB[0], bufA[1], bufB[1], tw, tid, 1, false);   __syncthreads();
    r4_stage(bufB[0], bufA[0], bufB[1], bufA[1], tw, tid, 4, false);   __syncthreads();
    r4_stage(bufA[0], bufB[0], bufA[1], bufB[1], tw, tid, 16, false);  __syncthreads();
    r4_stage(bufB[0], bufA[0], bufB[1], bufA[1], tw, tid, 64, false);  __syncthreads();
    r4_stage(bufA[0], bufB[0], bufA[1], bufB[1], tw, tid, 256, false); __syncthreads();

    // Hermitian-extended kernel multiply; fold 1/N and DPHI.
    const float scale = DPHI_F / 1024.0f;
    #pragma unroll
    for (int h = 0; h < 4; ++h) {
        const int k = tid + h * 256;
        const int kk = (k <= 512) ? k : (1024 - k);
        const float re = kr[kk] * scale;
        float im = ((k == 0) || (k == 512)) ? 0.0f : ki[kk] * scale;
        if (k > 512) im = -im;
        #pragma unroll
        for (int f = 0; f < 2; ++f) {
            const float2 z = bufB[f][k];
            bufB[f][k] = make_float2(re * z.x - im * z.y, re * z.y + im * z.x);
        }
    }
    __syncthreads();

    r4_stage(bufB[0], bufA[0], bufB[1], bufA[1], tw, tid, 1, true);   __syncthreads();
    r4_stage(bufA[0], bufB[0], bufA[1], bufB[1], tw, tid, 4, true);   __syncthreads();
    r4_stage(bufB[0], bufA[0], bufB[1], bufA[1], tw, tid, 16, true);  __syncthreads();
    r4_stage(bufA[0], bufB[0], bufA[1], bufB[1], tw, tid, 64, true);  __syncthreads();
    r4_stage(bufB[0], bufA[0], bufB[1], bufA[1], tw, tid, 256, true); __syncthreads();

    #pragma unroll
    for (int f = 0; f < 2; ++f) {
        float* r0 = base + f * 2048;
        float* r1 = r0 + 1024;
        #pragma unroll
        for (int h = 0; h < 4; ++h) {
            const int k = tid + h * 256;
            const float2 v = bufA[f][k];
            r0[k] = v.x;
            r1[k] = v.y;
        }
    }
}

// ---------------------------------------------------------------------------
// Kernel 2 (fast path): barrier-free backprojection. 1 wave per block.
// Lanes form an 8(i) x 8(j) patch replicated at 4 i-offsets (i-span 32,
// j-span 8): per-angle lane u-span <= 28 dwords < 32 banks -> conflict-free
// ds_read2. Per 8-angle chunk the wave privately stages 128-bin windows to
// its own LDS; intra-wave LDS ordering makes barriers unnecessary. All
// wave-uniform per-angle params come from d_ws via scalar loads.
// ---------------------------------------------------------------------------
__global__ __launch_bounds__(64, 4) void backproj_tab_kernel(const float* __restrict__ filt,
                                                             float* __restrict__ out,
                                                             const char* __restrict__ wsb) {
    __shared__ float win[8][128];
    const int l = threadIdx.x;
    // XCD swizzle: 4096 blocks -> each XCD owns 512 logical blocks = 2 batches.
    const int wg = blockIdx.x;
    const int lb = ((wg & 7) << 9) | (wg >> 3);
    const int b = lb >> 8;
    const int ist = (lb >> 5) & 7;       // i-strip of 32
    const int jst = lb & 31;             // j-strip of 8
    const int st = ist * 8 + (jst >> 2); // supertile for window table

    const float4* __restrict__ ang4 = (const float4*)(wsb + WS_ANG);
    const int2* __restrict__ kwT = ((const int2*)(wsb + WS_KW)) + st * PHI;

    const int ii = l & 7, jj = l >> 3;
    const int ip = ist * 32 + ii;        // pixel i = ip + 8p
    const int j = jst * 8 + jj;
    const float Xc = -1.0f + ((float)ip + 0.5f) * DXF;
    const float Yc = -1.0f + ((float)j + 0.5f) * DXF;

    const float* __restrict__ gb = filt + (size_t)b * (PHI * TS);
    float acc0 = 0.f, acc1 = 0.f, acc2 = 0.f, acc3 = 0.f;

    // stage chunk 0
    #pragma unroll
    for (int a = 0; a < 8; ++a) {
        const float* row = gb + (a << 10) + kwT[a].y;
        win[a][l] = row[l];
        win[a][l + 64] = row[l + 64];
    }

    for (int c = 0; c < PHI / 8; ++c) {
        float p0[8], p1[8];
        const bool more = (c + 1 < PHI / 8);
        if (more) {   // issue next chunk's loads into registers (uniform branch)
            #pragma unroll
            for (int a = 0; a < 8; ++a) {
                const int ang = c * 8 + 8 + a;
                const float* row = gb + ((size_t)ang << 10) + kwT[ang].y;
                p0[a] = row[l];
                p1[a] = row[l + 64];
            }
        }
        #pragma unroll
        for (int a = 0; a < 8; ++a) {
            const int ang = c * 8 + a;
            const float4 cv = ang4[ang];
            float u = fmaf(cv.y, Yc, fmaf(cv.x, Xc, __int_as_float(kwT[ang].x)));
            const float du = cv.z;       // 8-pixel i-step in index units
            {
                const int idx = (int)u; const float wf = fract_fast(u);
                const float g0 = win[a][idx], g1 = win[a][idx + 1];
                acc0 = fmaf(wf, g1 - g0, acc0 + g0); u += du;
            }
            {
                const int idx = (int)u; const float wf = fract_fast(u);
                const float g0 = win[a][idx], g1 = win[a][idx + 1];
                acc1 = fmaf(wf, g1 - g0, acc1 + g0); u += du;
            }
            {
                const int idx = (int)u; const float wf = fract_fast(u);
                const float g0 = win[a][idx], g1 = win[a][idx + 1];
                acc2 = fmaf(wf, g1 - g0, acc2 + g0); u += du;
            }
            {
                const int idx = (int)u; const float wf = fract_fast(u);
                const float g0 = win[a][idx], g1 = win[a][idx + 1];
                acc3 = fmaf(wf, g1 - g0, acc3 + g0);
            }
        }
        if (more) {   // write prefetched windows (in-order intra-wave LDS)
            #pragma unroll
            for (int a = 0; a < 8; ++a) {
                win[a][l] = p0[a];
                win[a][l + 64] = p1[a];
            }
        }
    }

    float* op = out + (((size_t)(b * NPIX + ip)) << 8) + j;
    op[0] = acc0;
    op[8 * NPIX] = acc1;
    op[16 * NPIX] = acc2;
    op[24 * NPIX] = acc3;
}

// ---------------------------------------------------------------------------
// Fallback backprojection (ws too small): R2's verified 256-thread kernel.
// ---------------------------------------------------------------------------
__global__ __launch_bounds__(256) void backproj_fb_kernel(const float* __restrict__ filt,
                                                          float* __restrict__ out) {
    __shared__ float2 csI[PHI];
    __shared__ float win[8 * 128];
    __shared__ float woffF[8];

    const int tid = threadIdx.x;
    const int wg = blockIdx.x;
    const int lb = ((wg & 7) << 7) | (wg >> 3);
    const int b = lb >> 6;
    const int tile = lb & 63;
    const int i0 = (tile >> 3) * 32;
    const int j0 = (tile & 7) * 32;

    for (int p = tid; p < PHI; p += 256) {
        const float ang = ((float)p + 0.5f) * (float)(3.14159265358979323846 / 720.0);
        float s, c;
        sincosf(ang, &s, &c);
        csI[p] = make_float2(c * INVDT, s * INVDT);
    }

    const int lane = tid & 63;
    const int wv = tid >> 6;
    const int ii = lane & 7;
    const int jj = lane >> 3;
    const int ip = i0 + ii;
    const int j = j0 + wv * 8 + jj;

    const float Xc = -1.0f + ((float)ip + 0.5f) * DXF;
    const float Yc = -1.0f + ((float)j + 0.5f) * DXF;

    const int r = tid >> 5;
    const int l32 = tid & 31;
    const float xlo = -1.0f + ((float)i0 + 0.5f) * DXF;
    const float xhi = -1.0f + ((float)i0 + 31.5f) * DXF;
    const float ylo = -1.0f + ((float)j0 + 0.5f) * DXF;
    const float yhi = -1.0f + ((float)j0 + 31.5f) * DXF;

    const float* gb = filt + (size_t)b * PHI * TS;
    float acc0 = 0.0f, acc1 = 0.0f, acc2 = 0.0f, acc3 = 0.0f;

    __syncthreads();

    {
        const float2 cs = csI[r];
        const float um = fminf(cs.x * xlo, cs.x * xhi) + fminf(cs.y * ylo, cs.y * yhi) + 511.5f;
        const int wb = (int)floorf(um) - 1;
        const float* grow = gb + (size_t)r * TS;
        #pragma unroll
        for (int h = 0; h < 4; ++h) {
            int gi = wb + l32 + 32 * h;
            gi = gi < 0 ? 0 : (gi > TS - 1 ? TS - 1 : gi);
            win[r * 128 + l32 + 32 * h] = grow[gi];
        }
        if (l32 == 0) woffF[r] = 511.5f + (float)(r * 128 - wb);
    }
    __syncthreads();

    for (int c = 0; c < PHI / 8; ++c) {
        float gp0 = 0.f, gp1 = 0.f, gp2 = 0.f, gp3 = 0.f;
        int wbn = 0;
        const bool more = (c + 1 < PHI / 8);
        if (more) {
            const int a = (c + 1) * 8 + r;
            const float2 cs = csI[a];
            const float um = fminf(cs.x * xlo, cs.x * xhi) + fminf(cs.y * ylo, cs.y * yhi) + 511.5f;
            wbn = (int)floorf(um) - 1;
            const float* grow = gb + (size_t)a * TS;
            int g0 = wbn + l32;      g0 = g0 < 0 ? 0 : (g0 > TS - 1 ? TS - 1 : g0);
            int g1 = wbn + l32 + 32; g1 = g1 < 0 ? 0 : (g1 > TS - 1 ? TS - 1 : g1);
            int g2 = wbn + l32 + 64; g2 = g2 < 0 ? 0 : (g2 > TS - 1 ? TS - 1 : g2);
            int g3 = wbn + l32 + 96; g3 = g3 < 0 ? 0 : (g3 > TS - 1 ? TS - 1 : g3);
            gp0 = grow[g0]; gp1 = grow[g1]; gp2 = grow[g2]; gp3 = grow[g3];
        }
        #pragma unroll
        for (int aa = 0; aa < 8; ++aa) {
            const float2 cs = csI[c * 8 + aa];
            const float offF = woffF[aa];
            float u = fmaf(cs.y, Yc, cs.x * Xc) + offF;
            const float dup = cs.x * 0.0625f;
            #pragma unroll
            for (int p = 0; p < 4; ++p) {
                const int idx = (int)u;
                const float wf = fract_fast(u);
                const float g0 = win[idx], g1 = win[idx + 1];
                if (p == 0) acc0 = fmaf(wf, g1 - g0, acc0 + g0);
                else if (p == 1) acc1 = fmaf(wf, g1 - g0, acc1 + g0);
                else if (p == 2) acc2 = fmaf(wf, g1 - g0, acc2 + g0);
                else acc3 = fmaf(wf, g1 - g0, acc3 + g0);
                u += dup;
            }
        }
        __syncthreads();
        if (more) {
            win[r * 128 + l32] = gp0;
            win[r * 128 + l32 + 32] = gp1;
            win[r * 128 + l32 + 64] = gp2;
            win[r * 128 + l32 + 96] = gp3;
            if (l32 == 0) woffF[r] = 511.5f + (float)(r * 128 - wbn);
        }
        __syncthreads();
    }

    const size_t ob = ((size_t)(b * NPIX + ip)) * NPIX + j;
    out[ob] = acc0;
    out[ob + 8 * NPIX] = acc1;
    out[ob + 16 * NPIX] = acc2;
    out[ob + 24 * NPIX] = acc3;
}

extern "C" void kernel_launch(void* const* d_in, const int* in_sizes, int n_in,
                              void* d_out, int out_size, void* d_ws, size_t ws_size,
                              hipStream_t stream) {
    float* sinos = (float*)d_in[0];          // [16,720,1024] f32, filtered in-place
    const float* kr = (const float*)d_in[1]; // [513]
    const float* ki = (const float*)d_in[2]; // [513]
    float* out = (float*)d_out;              // [16,256,256] f32

    char* wsb = nullptr;
    if (ws_size >= (size_t)WS_NEEDED && d_ws != nullptr) {
        wsb = (char*)d_ws;
        precompute_kernel<<<(512 + PHI + 64 * PHI + 255) / 256, 256, 0, stream>>>(wsb);
    }
    filter_fft_kernel<<<NB * PHI / 4, 256, 0, stream>>>(sinos, kr, ki, wsb);
    if (wsb) {
        backproj_tab_kernel<<<NB * 256, 64, 0, stream>>>(sinos, out, wsb);
    } else {
        backproj_fb_kernel<<<NB * 64, 256, 0, stream>>>(sinos, out);
    }
}

// Round 4
// 290.999 us; speedup vs baseline: 1.2237x; 1.0840x over previous
//
#include <hip/hip_runtime.h>

#define PHI 720
#define TS 1024
#define NB 16
#define NPIX 256

#define INVDT 362.03867196751236f      // 1024 / (2*sqrt(2))
#define DXF 0.0078125f                 // 2/256
#define DPHI_F 0.0043633231299858237f  // pi/720

// d_ws layout (bytes):
//   WS_TW : float2 tw[512]        FFT twiddles exp(-2pi i k/1024)
//   WS_ANG: float2 ang[360]       (cos*INVDT, sin*INVDT) for pair angle phi
//   WS_PT : uint4 [256][360]      per (rep-tile, angle-pair):
//           {bits(511.5-wbA), bits(511.5-wbC), wbA|wbB<<16, wbC|wbD<<16}
#define WS_TW 0
#define WS_ANG 4096
#define WS_PT 8192
#define WS_NEEDED (8192 + 256 * 360 * 16)

__device__ __forceinline__ float2 cmulf2(float2 a, float2 b) {
    return make_float2(a.x * b.x - a.y * b.y, a.x * b.y + a.y * b.x);
}
__device__ __forceinline__ float fract_fast(float x) {
#if __has_builtin(__builtin_amdgcn_fractf)
    return __builtin_amdgcn_fractf(x);
#else
    return x - floorf(x);
#endif
}

// ---------------------------------------------------------------------------
// Kernel 0: tables into d_ws (recomputed every launch; graph-safe).
// ---------------------------------------------------------------------------
__global__ __launch_bounds__(256) void precompute_kernel(char* __restrict__ wsb) {
    const int blk = blockIdx.x, tid = threadIdx.x;
    if (blk < 360) {
        const int e = blk * 256 + tid;                 // 92160 entries
        const unsigned repu = (unsigned)e / 360u;
        const int rep = (int)repu;
        const int a = e - rep * 360;
        const int ti = rep >> 4, tj = rep & 15;
        float s, c;
        sincosf(((float)a + 0.5f) * (3.14159265358979323846f / 720.0f), &s, &c);
        const float x0 = -1.0f + ((float)(ti * 8) + 0.5f) * DXF;
        const float x7 = x0 + 7.0f * DXF;
        const float y0 = -1.0f + ((float)(tj * 8) + 0.5f) * DXF;
        const float y7 = y0 + 7.0f * DXF;
        // c,s > 0 for phi in (0, pi/2): monotone extremes
        const float uTmin = (c * x0 + s * y0) * INVDT + 511.5f;
        const float uTmax = (c * x7 + s * y7) * INVDT + 511.5f;
        const float uUmin = (s * x0 - c * y7) * INVDT + 511.5f;
        const float uUmax = (s * x7 - c * y0) * INVDT + 511.5f;
        int wbA = (int)floorf(uTmin - 0.02f) - 1;                 // +T window
        int wbB = (int)floorf(1023.0f - uTmax - 0.02f) - 1;       // -T window
        int wbC = (int)floorf(uUmin - 0.02f) - 1;                 // +U window
        int wbD = (int)floorf(1023.0f - uUmax - 0.02f) - 1;       // -U window
        wbA = min(max(wbA, 0), 992);
        wbB = min(max(wbB, 0), 992);
        wbC = min(max(wbC, 0), 992);
        wbD = min(max(wbD, 0), 992);
        uint4 ent;
        ent.x = __float_as_uint(511.5f - (float)wbA);
        ent.y = __float_as_uint(511.5f - (float)wbC);
        ent.z = (unsigned)wbA | ((unsigned)wbB << 16);
        ent.w = (unsigned)wbC | ((unsigned)wbD << 16);
        ((uint4*)(wsb + WS_PT))[e] = ent;
    } else if (blk < 362) {
        const int k = (blk - 360) * 256 + tid;
        float s, c;
        sincosf((float)k * (6.28318530717958647692f / 1024.0f), &s, &c);
        ((float2*)(wsb + WS_TW))[k] = make_float2(c, -s);
    } else {
        const int a = (blk - 362) * 256 + tid;
        if (a < 360) {
            float s, c;
            sincosf(((float)a + 0.5f) * (3.14159265358979323846f / 720.0f), &s, &c);
            ((float2*)(wsb + WS_ANG))[a] = make_float2(c * INVDT, s * INVDT);
        }
    }
}

// ---------------------------------------------------------------------------
// Kernel 1: circular filtering row <- irfft(K * rfft(row)) * DPHI.
// Radix-4 Stockham, 5 fwd + 5 inv stages, 2 packed FFTs per block.
// (verified in R3; phase/DT factors of the reference cancel exactly)
// ---------------------------------------------------------------------------
__device__ __forceinline__ void r4_stage(const float2* __restrict__ s0, float2* __restrict__ d0,
                                         const float2* __restrict__ s1, float2* __restrict__ d1,
                                         const float2* __restrict__ tw, int tid, int m, bool inv) {
    const int q = tid & ~(m - 1);
    const int o = tid + 3 * q;
    float2 w1 = tw[q], w2 = tw[2 * q];
    if (inv) { w1.y = -w1.y; w2.y = -w2.y; }
    #pragma unroll
    for (int f = 0; f < 2; ++f) {
        const float2* s = f ? s1 : s0;
        float2* d = f ? d1 : d0;
        const float2 a = s[tid], b = s[tid + 256], c = s[tid + 512], e = s[tid + 768];
        const float2 A = make_float2(a.x + c.x, a.y + c.y);
        const float2 Bm = cmulf2(w1, make_float2(a.x - c.x, a.y - c.y));
        const float2 C = make_float2(b.x + e.x, b.y + e.y);
        const float2 Dm = cmulf2(w1, make_float2(b.x - e.x, b.y - e.y));
        const float2 D = inv ? make_float2(-Dm.y, Dm.x) : make_float2(Dm.y, -Dm.x);
        d[o]         = make_float2(A.x + C.x, A.y + C.y);
        d[o + m]     = make_float2(Bm.x + D.x, Bm.y + D.y);
        d[o + 2 * m] = cmulf2(w2, make_float2(A.x - C.x, A.y - C.y));
        d[o + 3 * m] = cmulf2(w2, make_float2(Bm.x - D.x, Bm.y - D.y));
    }
}

__global__ __launch_bounds__(256) void filter_fft_kernel(float* __restrict__ sinos,
                                                         const float* __restrict__ kr,
                                                         const float* __restrict__ ki,
                                                         const char* __restrict__ wsb) {
    __shared__ float2 bufA[2][1024];
    __shared__ float2 bufB[2][1024];
    __shared__ float2 tw[512];
    const int tid = threadIdx.x;
    const int wg = blockIdx.x;
    const int lb = (wg & 7) * 360 + (wg >> 3);
    float* base = sinos + (size_t)lb * 4096;

    #pragma unroll
    for (int f = 0; f < 2; ++f) {
        float* r0 = base + f * 2048;
        float* r1 = r0 + 1024;
        #pragma unroll
        for (int h = 0; h < 4; ++h) {
            const int k = tid + h * 256;
            bufA[f][k] = make_float2(r0[k], r1[k]);
        }
    }
    if (wsb) {
        const float2* tg = (const float2*)(wsb + WS_TW);
        tw[tid] = tg[tid];
        tw[tid + 256] = tg[tid + 256];
    } else {
        #pragma unroll
        for (int h = 0; h < 2; ++h) {
            const int k = tid + h * 256;
            float s, c;
            sincosf((float)k * (6.28318530717958647692f / 1024.0f), &s, &c);
            tw[k] = make_float2(c, -s);
        }
    }
    __syncthreads();

    r4_stage(bufA[0], bufB[0], bufA[1], bufB[1], tw, tid, 1, false);   __syncthreads();
    r4_stage(bufB[0], bufA[0], bufB[1], bufA[1], tw, tid, 4, false);   __syncthreads();
    r4_stage(bufA[0], bufB[0], bufA[1], bufB[1], tw, tid, 16, false);  __syncthreads();
    r4_stage(bufB[0], bufA[0], bufB[1], bufA[1], tw, tid, 64, false);  __syncthreads();
    r4_stage(bufA[0], bufB[0], bufA[1], bufB[1], tw, tid, 256, false); __syncthreads();

    const float scale = DPHI_F / 1024.0f;
    #pragma unroll
    for (int h = 0; h < 4; ++h) {
        const int k = tid + h * 256;
        const int kk = (k <= 512) ? k : (1024 - k);
        const float re = kr[kk] * scale;
        float im = ((k == 0) || (k == 512)) ? 0.0f : ki[kk] * scale;
        if (k > 512) im = -im;
        #pragma unroll
        for (int f = 0; f < 2; ++f) {
            const float2 z = bufB[f][k];
            bufB[f][k] = make_float2(re * z.x - im * z.y, re * z.y + im * z.x);
        }
    }
    __syncthreads();

    r4_stage(bufB[0], bufA[0], bufB[1], bufA[1], tw, tid, 1, true);   __syncthreads();
    r4_stage(bufA[0], bufB[0], bufA[1], bufB[1], tw, tid, 4, true);   __syncthreads();
    r4_stage(bufB[0], bufA[0], bufB[1], bufA[1], tw, tid, 16, true);  __syncthreads();
    r4_stage(bufA[0], bufB[0], bufA[1], bufB[1], tw, tid, 64, true);  __syncthreads();
    r4_stage(bufB[0], bufA[0], bufB[1], bufA[1], tw, tid, 256, true); __syncthreads();

    #pragma unroll
    for (int f = 0; f < 2; ++f) {
        float* r0 = base + f * 2048;
        float* r1 = r0 + 1024;
        #pragma unroll
        for (int h = 0; h < 4; ++h) {
            const int k = tid + h * 256;
            const float2 v = bufA[f][k];
            r0[k] = v.x;
            r1[k] = v.y;
        }
    }
}

// ---------------------------------------------------------------------------
// Kernel 2 (fast path): 4-fold-symmetric backprojection. 1 wave per block.
// Block = (batch, rep-tile quad): pixels p0=(i,j) in 8x8 tile T plus its
// three 90-degree rotations. For angle pair (phi_a, phi_a + pi/2) all 8
// contributions (4 pixels x 2 angles) use just two detector positions
// +-T, +-U -> one cvt/fract serves 4 lerps (reversed windows read
// descending with weight 1-w, via idxRev = 1022-wbF-wbR-idxFwd).
// LDS slot per pair: [Af|At|Bf|Bt|Cf|Ct|Df|Dt] x 32 dwords; each window
// pair is staged by one 64-lane load (lanes 0-31 phi-row, 32-63 theta-row)
// with SGPR base + static per-lane offset (zero VALU), double-buffered.
// ---------------------------------------------------------------------------
__global__ __launch_bounds__(64, 4) void backproj_sym_kernel(const float* __restrict__ filt,
                                                             float* __restrict__ out,
                                                             const char* __restrict__ wsb) {
    __shared__ float lds[2 * 4 * 256];
    const int l = threadIdx.x;
    // XCD swizzle: 4096 blocks -> each XCD owns 512 logical blocks = 2 batches.
    const int wg = blockIdx.x;
    const int lb = ((wg & 7) << 9) | (wg >> 3);
    const int b = lb >> 8;
    const int rep = lb & 255;
    const int ti = rep >> 4, tj = rep & 15;

    const float2* __restrict__ ang = (const float2*)(wsb + WS_ANG);
    const uint4* __restrict__ pt = ((const uint4*)(wsb + WS_PT)) + rep * 360;

    const int ii = l >> 3, jj = l & 7;
    const int ip = ti * 8 + ii, jp = tj * 8 + jj;
    const float Xc = -1.0f + ((float)ip + 0.5f) * DXF;
    const float Yc = -1.0f + ((float)jp + 0.5f) * DXF;
    // static per-lane byte offset: lanes 0-31 phi-row[k], 32-63 theta-row[k]
    const int vbyte = ((l & 31) + ((l >> 5) * (360 * 1024))) * 4;
    const float* __restrict__ gb = filt + (size_t)b * (PHI * TS);

    float a0 = 0.f, a1 = 0.f, a2 = 0.f, a3 = 0.f;
    float pf[4][4];

#define STAGE(CH) { \
    _Pragma("unroll") \
    for (int p = 0; p < 4; ++p) { \
        const int ap = (CH) * 4 + p; \
        const uint4 e = pt[ap]; \
        const char* rp = (const char*)(gb + (ap << 10)); \
        pf[p][0] = *(const float*)(rp + ((e.z & 0xFFFFu) << 2) + vbyte); \
        pf[p][1] = *(const float*)(rp + ((e.z >> 16) << 2) + vbyte); \
        pf[p][2] = *(const float*)(rp + ((e.w & 0xFFFFu) << 2) + vbyte); \
        pf[p][3] = *(const float*)(rp + ((e.w >> 16) << 2) + vbyte); \
    } }

#define WRITE(BUF) { \
    _Pragma("unroll") \
    for (int p = 0; p < 4; ++p) { \
        _Pragma("unroll") \
        for (int w = 0; w < 4; ++w) \
            lds[(BUF) * 1024 + p * 256 + w * 64 + l] = pf[p][w]; \
    } }

#define COMPUTE(BUF, CH) { \
    _Pragma("unroll") \
    for (int p = 0; p < 4; ++p) { \
        const int ap = (CH) * 4 + p; \
        const uint4 e = pt[ap]; \
        const float2 cs = ang[ap]; \
        const float* slot = &lds[(BUF) * 1024 + p * 256]; \
        const float kFA = __uint_as_float(e.x), kFC = __uint_as_float(e.y); \
        const int wbA = (int)(e.z & 0xFFFFu), wbB = (int)(e.z >> 16); \
        const int wbC = (int)(e.w & 0xFFFFu), wbD = (int)(e.w >> 16); \
        const float uT = fmaf(cs.x, Xc, fmaf(cs.y, Yc, kFA)); \
        const float uU = fmaf(cs.y, Xc, fmaf(cs.x, -Yc, kFC)); \
        const int iA = (int)uT; const float wT = fract_fast(uT); \
        const int iC = (int)uU; const float wU = fract_fast(uU); \
        const int iB = 1022 - wbA - wbB - iA; \
        const int iD = 1022 - wbC - wbD - iC; \
        { const float g0 = slot[iA],       g1 = slot[iA + 1]; \
          const float h0 = slot[iA + 32],  h1 = slot[iA + 33]; \
          a0 = fmaf(wT, g1 - g0, a0 + g0); a1 = fmaf(wT, h1 - h0, a1 + h0); } \
        { const float g0 = slot[64 + iB],  g1 = slot[65 + iB]; \
          const float h0 = slot[96 + iB],  h1 = slot[97 + iB]; \
          a2 = fmaf(wT, g0 - g1, a2 + g1); a3 = fmaf(wT, h0 - h1, a3 + h1); } \
        { const float g0 = slot[128 + iC], g1 = slot[129 + iC]; \
          const float h0 = slot[160 + iC], h1 = slot[161 + iC]; \
          a1 = fmaf(wU, g1 - g0, a1 + g0); a2 = fmaf(wU, h1 - h0, a2 + h0); } \
        { const float g0 = slot[192 + iD], g1 = slot[193 + iD]; \
          const float h0 = slot[224 + iD], h1 = slot[225 + iD]; \
          a3 = fmaf(wU, g0 - g1, a3 + g1); a0 = fmaf(wU, h0 - h1, a0 + h1); } \
    } }

    STAGE(0); WRITE(0);
    for (int cc = 0; cc < 44; ++cc) {
        STAGE(2 * cc + 1);
        COMPUTE(0, 2 * cc);
        WRITE(1);
        STAGE(2 * cc + 2);
        COMPUTE(1, 2 * cc + 1);
        WRITE(0);
    }
    STAGE(89);
    COMPUTE(0, 88);
    WRITE(1);
    COMPUTE(1, 89);

#undef STAGE
#undef WRITE
#undef COMPUTE

    const int bb = b << 8;
    out[((size_t)((bb + ip) << 8)) + jp]                    = a0;
    out[((size_t)((bb + 255 - jp) << 8)) + ip]              = a1;
    out[((size_t)((bb + 255 - ip) << 8)) + (255 - jp)]      = a2;
    out[((size_t)((bb + jp) << 8)) + (255 - ip)]            = a3;
}

// ---------------------------------------------------------------------------
// Fallback backprojection (ws too small): R2's verified 256-thread kernel.
// ---------------------------------------------------------------------------
__global__ __launch_bounds__(256) void backproj_fb_kernel(const float* __restrict__ filt,
                                                          float* __restrict__ out) {
    __shared__ float2 csI[PHI];
    __shared__ float win[8 * 128];
    __shared__ float woffF[8];

    const int tid = threadIdx.x;
    const int wg = blockIdx.x;
    const int lb = ((wg & 7) << 7) | (wg >> 3);
    const int b = lb >> 6;
    const int tile = lb & 63;
    const int i0 = (tile >> 3) * 32;
    const int j0 = (tile & 7) * 32;

    for (int p = tid; p < PHI; p += 256) {
        const float angv = ((float)p + 0.5f) * (float)(3.14159265358979323846 / 720.0);
        float s, c;
        sincosf(angv, &s, &c);
        csI[p] = make_float2(c * INVDT, s * INVDT);
    }

    const int lane = tid & 63;
    const int wv = tid >> 6;
    const int ii = lane & 7;
    const int jj = lane >> 3;
    const int ipx = i0 + ii;
    const int j = j0 + wv * 8 + jj;

    const float Xc = -1.0f + ((float)ipx + 0.5f) * DXF;
    const float Yc = -1.0f + ((float)j + 0.5f) * DXF;

    const int r = tid >> 5;
    const int l32 = tid & 31;
    const float xlo = -1.0f + ((float)i0 + 0.5f) * DXF;
    const float xhi = -1.0f + ((float)i0 + 31.5f) * DXF;
    const float ylo = -1.0f + ((float)j0 + 0.5f) * DXF;
    const float yhi = -1.0f + ((float)j0 + 31.5f) * DXF;

    const float* gb = filt + (size_t)b * PHI * TS;
    float acc0 = 0.f, acc1 = 0.f, acc2 = 0.f, acc3 = 0.f;

    __syncthreads();

    {
        const float2 cs = csI[r];
        const float um = fminf(cs.x * xlo, cs.x * xhi) + fminf(cs.y * ylo, cs.y * yhi) + 511.5f;
        const int wb = (int)floorf(um) - 1;
        const float* grow = gb + (size_t)r * TS;
        #pragma unroll
        for (int h = 0; h < 4; ++h) {
            int gi = wb + l32 + 32 * h;
            gi = gi < 0 ? 0 : (gi > TS - 1 ? TS - 1 : gi);
            win[r * 128 + l32 + 32 * h] = grow[gi];
        }
        if (l32 == 0) woffF[r] = 511.5f + (float)(r * 128 - wb);
    }
    __syncthreads();

    for (int c = 0; c < PHI / 8; ++c) {
        float gp0 = 0.f, gp1 = 0.f, gp2 = 0.f, gp3 = 0.f;
        int wbn = 0;
        const bool more = (c + 1 < PHI / 8);
        if (more) {
            const int a = (c + 1) * 8 + r;
            const float2 cs = csI[a];
            const float um = fminf(cs.x * xlo, cs.x * xhi) + fminf(cs.y * ylo, cs.y * yhi) + 511.5f;
            wbn = (int)floorf(um) - 1;
            const float* grow = gb + (size_t)a * TS;
            int g0 = wbn + l32;      g0 = g0 < 0 ? 0 : (g0 > TS - 1 ? TS - 1 : g0);
            int g1 = wbn + l32 + 32; g1 = g1 < 0 ? 0 : (g1 > TS - 1 ? TS - 1 : g1);
            int g2 = wbn + l32 + 64; g2 = g2 < 0 ? 0 : (g2 > TS - 1 ? TS - 1 : g2);
            int g3 = wbn + l32 + 96; g3 = g3 < 0 ? 0 : (g3 > TS - 1 ? TS - 1 : g3);
            gp0 = grow[g0]; gp1 = grow[g1]; gp2 = grow[g2]; gp3 = grow[g3];
        }
        #pragma unroll
        for (int aa = 0; aa < 8; ++aa) {
            const float2 cs = csI[c * 8 + aa];
            const float offF = woffF[aa];
            float u = fmaf(cs.y, Yc, cs.x * Xc) + offF;
            const float dup = cs.x * 0.0625f;
            #pragma unroll
            for (int p = 0; p < 4; ++p) {
                const int idx = (int)u;
                const float wf = fract_fast(u);
                const float g0 = win[idx], g1 = win[idx + 1];
                if (p == 0) acc0 = fmaf(wf, g1 - g0, acc0 + g0);
                else if (p == 1) acc1 = fmaf(wf, g1 - g0, acc1 + g0);
                else if (p == 2) acc2 = fmaf(wf, g1 - g0, acc2 + g0);
                else acc3 = fmaf(wf, g1 - g0, acc3 + g0);
                u += dup;
            }
        }
        __syncthreads();
        if (more) {
            win[r * 128 + l32] = gp0;
            win[r * 128 + l32 + 32] = gp1;
            win[r * 128 + l32 + 64] = gp2;
            win[r * 128 + l32 + 96] = gp3;
            if (l32 == 0) woffF[r] = 511.5f + (float)(r * 128 - wbn);
        }
        __syncthreads();
    }

    const size_t ob = ((size_t)(b * NPIX + ipx)) * NPIX + j;
    out[ob] = acc0;
    out[ob + 8 * NPIX] = acc1;
    out[ob + 16 * NPIX] = acc2;
    out[ob + 24 * NPIX] = acc3;
}

extern "C" void kernel_launch(void* const* d_in, const int* in_sizes, int n_in,
                              void* d_out, int out_size, void* d_ws, size_t ws_size,
                              hipStream_t stream) {
    float* sinos = (float*)d_in[0];          // [16,720,1024] f32, filtered in-place
    const float* kr = (const float*)d_in[1]; // [513]
    const float* ki = (const float*)d_in[2]; // [513]
    float* out = (float*)d_out;              // [16,256,256] f32

    char* wsb = nullptr;
    if (ws_size >= (size_t)WS_NEEDED && d_ws != nullptr) {
        wsb = (char*)d_ws;
        precompute_kernel<<<364, 256, 0, stream>>>(wsb);
    }
    filter_fft_kernel<<<NB * PHI / 4, 256, 0, stream>>>(sinos, kr, ki, wsb);
    if (wsb) {
        backproj_sym_kernel<<<4096, 64, 0, stream>>>(sinos, out, wsb);
    } else {
        backproj_fb_kernel<<<NB * 64, 256, 0, stream>>>(sinos, out);
    }
}

// Round 7
// 265.141 us; speedup vs baseline: 1.3430x; 1.0975x over previous
//
#include <hip/hip_runtime.h>

#define PHI 720
#define TS 1024
#define NB 16
#define NPIX 256

#define INVDT 362.03867196751236f      // 1024 / (2*sqrt(2))
#define DXF 0.0078125f                 // 2/256
#define DPHI_F 0.0043633231299858237f  // pi/720

// d_ws layout (bytes):
//   WS_TW : float2 tw[512]        FFT twiddles exp(-2pi i k/1024)
//   WS_ANG: float2 ang[360]       (cos*INVDT, sin*INVDT) for pair angle phi
//   WS_PT : uint4 [256][360]      per (rep-tile, angle-pair):
//           {bits(511.5-wbA), bits(511.5-wbC), wbA|wbB<<16, wbC|wbD<<16}
#define WS_TW 0
#define WS_ANG 4096
#define WS_PT 8192
#define WS_NEEDED (8192 + 256 * 360 * 16)

__device__ __forceinline__ float2 cmulf2(float2 a, float2 b) {
    return make_float2(a.x * b.x - a.y * b.y, a.x * b.y + a.y * b.x);
}
__device__ __forceinline__ float fract_fast(float x) {
#if __has_builtin(__builtin_amdgcn_fractf)
    return __builtin_amdgcn_fractf(x);
#else
    return x - floorf(x);
#endif
}

// ---------------------------------------------------------------------------
// Kernel 0: tables into d_ws (recomputed every launch; graph-safe).
// (verified R4)
// ---------------------------------------------------------------------------
__global__ __launch_bounds__(256) void precompute_kernel(char* __restrict__ wsb) {
    const int blk = blockIdx.x, tid = threadIdx.x;
    if (blk < 360) {
        const int e = blk * 256 + tid;                 // 92160 entries
        const unsigned repu = (unsigned)e / 360u;
        const int rep = (int)repu;
        const int a = e - rep * 360;
        const int ti = rep >> 4, tj = rep & 15;
        float s, c;
        sincosf(((float)a + 0.5f) * (3.14159265358979323846f / 720.0f), &s, &c);
        const float x0 = -1.0f + ((float)(ti * 8) + 0.5f) * DXF;
        const float x7 = x0 + 7.0f * DXF;
        const float y0 = -1.0f + ((float)(tj * 8) + 0.5f) * DXF;
        const float y7 = y0 + 7.0f * DXF;
        const float uTmin = (c * x0 + s * y0) * INVDT + 511.5f;
        const float uTmax = (c * x7 + s * y7) * INVDT + 511.5f;
        const float uUmin = (s * x0 - c * y7) * INVDT + 511.5f;
        const float uUmax = (s * x7 - c * y0) * INVDT + 511.5f;
        int wbA = (int)floorf(uTmin - 0.02f) - 1;                 // +T window
        int wbB = (int)floorf(1023.0f - uTmax - 0.02f) - 1;       // -T window
        int wbC = (int)floorf(uUmin - 0.02f) - 1;                 // +U window
        int wbD = (int)floorf(1023.0f - uUmax - 0.02f) - 1;       // -U window
        wbA = min(max(wbA, 0), 992);
        wbB = min(max(wbB, 0), 992);
        wbC = min(max(wbC, 0), 992);
        wbD = min(max(wbD, 0), 992);
        uint4 ent;
        ent.x = __float_as_uint(511.5f - (float)wbA);
        ent.y = __float_as_uint(511.5f - (float)wbC);
        ent.z = (unsigned)wbA | ((unsigned)wbB << 16);
        ent.w = (unsigned)wbC | ((unsigned)wbD << 16);
        ((uint4*)(wsb + WS_PT))[e] = ent;
    } else if (blk < 362) {
        const int k = (blk - 360) * 256 + tid;
        float s, c;
        sincosf((float)k * (6.28318530717958647692f / 1024.0f), &s, &c);
        ((float2*)(wsb + WS_TW))[k] = make_float2(c, -s);
    } else {
        const int a = (blk - 362) * 256 + tid;
        if (a < 360) {
            float s, c;
            sincosf(((float)a + 0.5f) * (3.14159265358979323846f / 720.0f), &s, &c);
            ((float2*)(wsb + WS_ANG))[a] = make_float2(c * INVDT, s * INVDT);
        }
    }
}

// ---------------------------------------------------------------------------
// Kernel 1: circular filtering row <- irfft(K * rfft(row)) * DPHI.
// Radix-4 Stockham (verified R3/R4); spectral multiply FUSED into the
// first inverse stage's loads (saves one LDS pass + one barrier).
// ---------------------------------------------------------------------------
__device__ __forceinline__ void r4_stage(const float2* __restrict__ s0, float2* __restrict__ d0,
                                         const float2* __restrict__ s1, float2* __restrict__ d1,
                                         const float2* __restrict__ tw, int tid, int m, bool inv) {
    const int q = tid & ~(m - 1);
    const int o = tid + 3 * q;
    float2 w1 = tw[q], w2 = tw[2 * q];
    if (inv) { w1.y = -w1.y; w2.y = -w2.y; }
    #pragma unroll
    for (int f = 0; f < 2; ++f) {
        const float2* s = f ? s1 : s0;
        float2* d = f ? d1 : d0;
        const float2 a = s[tid], b = s[tid + 256], c = s[tid + 512], e = s[tid + 768];
        const float2 A = make_float2(a.x + c.x, a.y + c.y);
        const float2 Bm = cmulf2(w1, make_float2(a.x - c.x, a.y - c.y));
        const float2 C = make_float2(b.x + e.x, b.y + e.y);
        const float2 Dm = cmulf2(w1, make_float2(b.x - e.x, b.y - e.y));
        const float2 D = inv ? make_float2(-Dm.y, Dm.x) : make_float2(Dm.y, -Dm.x);
        d[o]         = make_float2(A.x + C.x, A.y + C.y);
        d[o + m]     = make_float2(Bm.x + D.x, Bm.y + D.y);
        d[o + 2 * m] = cmulf2(w2, make_float2(A.x - C.x, A.y - C.y));
        d[o + 3 * m] = cmulf2(w2, make_float2(Bm.x - D.x, Bm.y - D.y));
    }
}

__device__ __forceinline__ float2 kfac(const float* __restrict__ kr,
                                       const float* __restrict__ ki, int k, float scale) {
    const int kk = (k <= 512) ? k : (1024 - k);
    const float re = kr[kk] * scale;
    float im = ((k == 0) || (k == 512)) ? 0.0f : ki[kk] * scale;
    if (k > 512) im = -im;
    return make_float2(re, im);
}

__global__ __launch_bounds__(256) void filter_fft_kernel(float* __restrict__ sinos,
                                                         const float* __restrict__ kr,
                                                         const float* __restrict__ ki,
                                                         const char* __restrict__ wsb) {
    __shared__ float2 bufA[2][1024];
    __shared__ float2 bufB[2][1024];
    __shared__ float2 tw[512];
    const int tid = threadIdx.x;
    const int wg = blockIdx.x;
    const int lb = (wg & 7) * 360 + (wg >> 3);
    float* base = sinos + (size_t)lb * 4096;

    #pragma unroll
    for (int f = 0; f < 2; ++f) {
        float* r0 = base + f * 2048;
        float* r1 = r0 + 1024;
        #pragma unroll
        for (int h = 0; h < 4; ++h) {
            const int k = tid + h * 256;
            bufA[f][k] = make_float2(r0[k], r1[k]);
        }
    }
    if (wsb) {
        const float2* tg = (const float2*)(wsb + WS_TW);
        tw[tid] = tg[tid];
        tw[tid + 256] = tg[tid + 256];
    } else {
        #pragma unroll
        for (int h = 0; h < 2; ++h) {
            const int k = tid + h * 256;
            float s, c;
            sincosf((float)k * (6.28318530717958647692f / 1024.0f), &s, &c);
            tw[k] = make_float2(c, -s);
        }
    }
    __syncthreads();

    r4_stage(bufA[0], bufB[0], bufA[1], bufB[1], tw, tid, 1, false);   __syncthreads();
    r4_stage(bufB[0], bufA[0], bufB[1], bufA[1], tw, tid, 4, false);   __syncthreads();
    r4_stage(bufA[0], bufB[0], bufA[1], bufB[1], tw, tid, 16, false);  __syncthreads();
    r4_stage(bufB[0], bufA[0], bufB[1], bufA[1], tw, tid, 64, false);  __syncthreads();
    r4_stage(bufA[0], bufB[0], bufA[1], bufB[1], tw, tid, 256, false); __syncthreads();

    // fused: first inverse stage (m=1) with K-multiply on the loads
    {
        const float scale = DPHI_F / 1024.0f;
        const int q = tid;
        const int o = 4 * tid;
        float2 w1 = tw[q], w2 = tw[2 * q];
        w1.y = -w1.y; w2.y = -w2.y;
        const float2 f0 = kfac(kr, ki, tid, scale);
        const float2 f1 = kfac(kr, ki, tid + 256, scale);
        const float2 f2 = kfac(kr, ki, tid + 512, scale);
        const float2 f3 = kfac(kr, ki, tid + 768, scale);
        #pragma unroll
        for (int f = 0; f < 2; ++f) {
            const float2* s = bufB[f];
            float2* d = bufA[f];
            const float2 a = cmulf2(f0, s[tid]);
            const float2 b = cmulf2(f1, s[tid + 256]);
            const float2 c = cmulf2(f2, s[tid + 512]);
            const float2 e = cmulf2(f3, s[tid + 768]);
            const float2 A = make_float2(a.x + c.x, a.y + c.y);
            const float2 Bm = cmulf2(w1, make_float2(a.x - c.x, a.y - c.y));
            const float2 C = make_float2(b.x + e.x, b.y + e.y);
            const float2 Dm = cmulf2(w1, make_float2(b.x - e.x, b.y - e.y));
            const float2 D = make_float2(-Dm.y, Dm.x);
            d[o]     = make_float2(A.x + C.x, A.y + C.y);
            d[o + 1] = make_float2(Bm.x + D.x, Bm.y + D.y);
            d[o + 2] = cmulf2(w2, make_float2(A.x - C.x, A.y - C.y));
            d[o + 3] = cmulf2(w2, make_float2(Bm.x - D.x, Bm.y - D.y));
        }
    }
    __syncthreads();

    r4_stage(bufA[0], bufB[0], bufA[1], bufB[1], tw, tid, 4, true);   __syncthreads();
    r4_stage(bufB[0], bufA[0], bufB[1], bufA[1], tw, tid, 16, true);  __syncthreads();
    r4_stage(bufA[0], bufB[0], bufA[1], bufB[1], tw, tid, 64, true);  __syncthreads();
    r4_stage(bufB[0], bufA[0], bufB[1], bufA[1], tw, tid, 256, true); __syncthreads();

    #pragma unroll
    for (int f = 0; f < 2; ++f) {
        float* r0 = base + f * 2048;
        float* r1 = r0 + 1024;
        #pragma unroll
        for (int h = 0; h < 4; ++h) {
            const int k = tid + h * 256;
            const float2 v = bufA[f][k];
            r0[k] = v.x;
            r1[k] = v.y;
        }
    }
}

// ---------------------------------------------------------------------------
// Kernel 2 (fast path): 4-fold-symmetric backprojection, 2 independent waves
// per block (each owns half the angle pairs, private LDS half, zero
// barriers), atomicAdd outputs (out pre-zeroed; exactly 2 contributions per
// pixel, fp add commutes). Index math identical to verified R4 kernel.
// ---------------------------------------------------------------------------
__global__ __launch_bounds__(128, 8) void backproj_sym_kernel(const float* __restrict__ filt,
                                                              float* __restrict__ out,
                                                              const char* __restrict__ wsb) {
    __shared__ float lds[2048];      // [wave:2][buf:2][pair:2][256]
    const int tid = threadIdx.x;
    const int hf = __builtin_amdgcn_readfirstlane(tid >> 6);  // wave id, scalar
    const int l = tid & 63;
    // XCD swizzle: 4096 blocks -> each XCD owns 512 logical blocks = 2 batches.
    const int wg = blockIdx.x;
    const int lb = ((wg & 7) << 9) | (wg >> 3);
    const int b = lb >> 8;
    const int rep = lb & 255;
    const int ti = rep >> 4, tj = rep & 15;

    const float2* __restrict__ ang = (const float2*)(wsb + WS_ANG);
    const uint4* __restrict__ pt = ((const uint4*)(wsb + WS_PT)) + rep * 360;

    const int ii = l >> 3, jj = l & 7;
    const int ip = ti * 8 + ii, jp = tj * 8 + jj;
    const float Xc = -1.0f + ((float)ip + 0.5f) * DXF;
    const float Yc = -1.0f + ((float)jp + 0.5f) * DXF;
    // static per-lane byte offset: lanes 0-31 phi-row[k], 32-63 theta-row[k]
    const int vbyte = ((l & 31) + ((l >> 5) * (360 * 1024))) * 4;
    const float* __restrict__ gb = filt + (size_t)b * (PHI * TS);
    const int lbase = hf * 1024;

    float a0 = 0.f, a1 = 0.f, a2 = 0.f, a3 = 0.f;
    float pf[2][4];

#define STAGE(CH) { \
    _Pragma("unroll") \
    for (int p = 0; p < 2; ++p) { \
        const int ap = hf * 180 + (CH) * 2 + p; \
        const uint4 e = pt[ap]; \
        const char* rp = (const char*)(gb + (ap << 10)); \
        pf[p][0] = *(const float*)(rp + ((e.z & 0xFFFFu) << 2) + vbyte); \
        pf[p][1] = *(const float*)(rp + ((e.z >> 16) << 2) + vbyte); \
        pf[p][2] = *(const float*)(rp + ((e.w & 0xFFFFu) << 2) + vbyte); \
        pf[p][3] = *(const float*)(rp + ((e.w >> 16) << 2) + vbyte); \
    } }

#define WRITE(BUF) { \
    _Pragma("unroll") \
    for (int p = 0; p < 2; ++p) { \
        _Pragma("unroll") \
        for (int w = 0; w < 4; ++w) \
            lds[lbase + (BUF) * 512 + p * 256 + w * 64 + l] = pf[p][w]; \
    } }

#define COMPUTE(BUF, CH) { \
    _Pragma("unroll") \
    for (int p = 0; p < 2; ++p) { \
        const int ap = hf * 180 + (CH) * 2 + p; \
        const uint4 e = pt[ap]; \
        const float2 cs = ang[ap]; \
        const float* slot = &lds[lbase + (BUF) * 512 + p * 256]; \
        const float kFA = __uint_as_float(e.x), kFC = __uint_as_float(e.y); \
        const int wbA = (int)(e.z & 0xFFFFu), wbB = (int)(e.z >> 16); \
        const int wbC = (int)(e.w & 0xFFFFu), wbD = (int)(e.w >> 16); \
        const float uT = fmaf(cs.x, Xc, fmaf(cs.y, Yc, kFA)); \
        const float uU = fmaf(cs.y, Xc, fmaf(cs.x, -Yc, kFC)); \
        const int iA = (int)uT; const float wT = fract_fast(uT); const float oT = 1.0f - wT; \
        const int iC = (int)uU; const float wU = fract_fast(uU); const float oU = 1.0f - wU; \
        const int iB = 1022 - wbA - wbB - iA; \
        const int iD = 1022 - wbC - wbD - iC; \
        { const float g0 = slot[iA],       g1 = slot[iA + 1]; \
          const float h0 = slot[iA + 32],  h1 = slot[iA + 33]; \
          a0 = fmaf(g0, oT, a0); a0 = fmaf(g1, wT, a0); \
          a1 = fmaf(h0, oT, a1); a1 = fmaf(h1, wT, a1); } \
        { const float g0 = slot[64 + iB],  g1 = slot[65 + iB]; \
          const float h0 = slot[96 + iB],  h1 = slot[97 + iB]; \
          a2 = fmaf(g1, oT, a2); a2 = fmaf(g0, wT, a2); \
          a3 = fmaf(h1, oT, a3); a3 = fmaf(h0, wT, a3); } \
        { const float g0 = slot[128 + iC], g1 = slot[129 + iC]; \
          const float h0 = slot[160 + iC], h1 = slot[161 + iC]; \
          a1 = fmaf(g0, oU, a1); a1 = fmaf(g1, wU, a1); \
          a2 = fmaf(h0, oU, a2); a2 = fmaf(h1, wU, a2); } \
        { const float g0 = slot[192 + iD], g1 = slot[193 + iD]; \
          const float h0 = slot[224 + iD], h1 = slot[225 + iD]; \
          a3 = fmaf(g1, oU, a3); a3 = fmaf(g0, wU, a3); \
          a0 = fmaf(h1, oU, a0); a0 = fmaf(h0, wU, a0); } \
    } }

    STAGE(0); WRITE(0);
    for (int cc = 0; cc < 44; ++cc) {
        STAGE(2 * cc + 1);
        COMPUTE(0, 2 * cc);
        WRITE(1);
        STAGE(2 * cc + 2);
        COMPUTE(1, 2 * cc + 1);
        WRITE(0);
    }
    STAGE(89);
    COMPUTE(0, 88);
    WRITE(1);
    COMPUTE(1, 89);

#undef STAGE
#undef WRITE
#undef COMPUTE

    const int bb = b << 8;
    atomicAdd(&out[((size_t)((bb + ip) << 8)) + jp], a0);
    atomicAdd(&out[((size_t)((bb + 255 - jp) << 8)) + ip], a1);
    atomicAdd(&out[((size_t)((bb + 255 - ip) << 8)) + (255 - jp)], a2);
    atomicAdd(&out[((size_t)((bb + jp) << 8)) + (255 - ip)], a3);
}

// ---------------------------------------------------------------------------
// Fallback backprojection (ws too small): R2's verified 256-thread kernel.
// ---------------------------------------------------------------------------
__global__ __launch_bounds__(256) void backproj_fb_kernel(const float* __restrict__ filt,
                                                          float* __restrict__ out) {
    __shared__ float2 csI[PHI];
    __shared__ float win[8 * 128];
    __shared__ float woffF[8];

    const int tid = threadIdx.x;
    const int wg = blockIdx.x;
    const int lb = ((wg & 7) << 7) | (wg >> 3);
    const int b = lb >> 6;
    const int tile = lb & 63;
    const int i0 = (tile >> 3) * 32;
    const int j0 = (tile & 7) * 32;

    for (int p = tid; p < PHI; p += 256) {
        const float angv = ((float)p + 0.5f) * (float)(3.14159265358979323846 / 720.0);
        float s, c;
        sincosf(angv, &s, &c);
        csI[p] = make_float2(c * INVDT, s * INVDT);
    }

    const int lane = tid & 63;
    const int wv = tid >> 6;
    const int ii = lane & 7;
    const int jj = lane >> 3;
    const int ipx = i0 + ii;
    const int j = j0 + wv * 8 + jj;

    const float Xc = -1.0f + ((float)ipx + 0.5f) * DXF;
    const float Yc = -1.0f + ((float)j + 0.5f) * DXF;

    const int r = tid >> 5;
    const int l32 = tid & 31;
    const float xlo = -1.0f + ((float)i0 + 0.5f) * DXF;
    const float xhi = -1.0f + ((float)i0 + 31.5f) * DXF;
    const float ylo = -1.0f + ((float)j0 + 0.5f) * DXF;
    const float yhi = -1.0f + ((float)j0 + 31.5f) * DXF;

    const float* gb = filt + (size_t)b * PHI * TS;
    float acc0 = 0.f, acc1 = 0.f, acc2 = 0.f, acc3 = 0.f;

    __syncthreads();

    {
        const float2 cs = csI[r];
        const float um = fminf(cs.x * xlo, cs.x * xhi) + fminf(cs.y * ylo, cs.y * yhi) + 511.5f;
        const int wb = (int)floorf(um) - 1;
        const float* grow = gb + (size_t)r * TS;
        #pragma unroll
        for (int h = 0; h < 4; ++h) {
            int gi = wb + l32 + 32 * h;
            gi = gi < 0 ? 0 : (gi > TS - 1 ? TS - 1 : gi);
            win[r * 128 + l32 + 32 * h] = grow[gi];
        }
        if (l32 == 0) woffF[r] = 511.5f + (float)(r * 128 - wb);
    }
    __syncthreads();

    for (int c = 0; c < PHI / 8; ++c) {
        float gp0 = 0.f, gp1 = 0.f, gp2 = 0.f, gp3 = 0.f;
        int wbn = 0;
        const bool more = (c + 1 < PHI / 8);
        if (more) {
            const int a = (c + 1) * 8 + r;
            const float2 cs = csI[a];
            const float um = fminf(cs.x * xlo, cs.x * xhi) + fminf(cs.y * ylo, cs.y * yhi) + 511.5f;
            wbn = (int)floorf(um) - 1;
            const float* grow = gb + (size_t)a * TS;
            int g0 = wbn + l32;      g0 = g0 < 0 ? 0 : (g0 > TS - 1 ? TS - 1 : g0);
            int g1 = wbn + l32 + 32; g1 = g1 < 0 ? 0 : (g1 > TS - 1 ? TS - 1 : g1);
            int g2 = wbn + l32 + 64; g2 = g2 < 0 ? 0 : (g2 > TS - 1 ? TS - 1 : g2);
            int g3 = wbn + l32 + 96; g3 = g3 < 0 ? 0 : (g3 > TS - 1 ? TS - 1 : g3);
            gp0 = grow[g0]; gp1 = grow[g1]; gp2 = grow[g2]; gp3 = grow[g3];
        }
        #pragma unroll
        for (int aa = 0; aa < 8; ++aa) {
            const float2 cs = csI[c * 8 + aa];
            const float offF = woffF[aa];
            float u = fmaf(cs.y, Yc, cs.x * Xc) + offF;
            const float dup = cs.x * 0.0625f;
            #pragma unroll
            for (int p = 0; p < 4; ++p) {
                const int idx = (int)u;
                const float wf = fract_fast(u);
                const float g0 = win[idx], g1 = win[idx + 1];
                if (p == 0) acc0 = fmaf(wf, g1 - g0, acc0 + g0);
                else if (p == 1) acc1 = fmaf(wf, g1 - g0, acc1 + g0);
                else if (p == 2) acc2 = fmaf(wf, g1 - g0, acc2 + g0);
                else acc3 = fmaf(wf, g1 - g0, acc3 + g0);
                u += dup;
            }
        }
        __syncthreads();
        if (more) {
            win[r * 128 + l32] = gp0;
            win[r * 128 + l32 + 32] = gp1;
            win[r * 128 + l32 + 64] = gp2;
            win[r * 128 + l32 + 96] = gp3;
            if (l32 == 0) woffF[r] = 511.5f + (float)(r * 128 - wbn);
        }
        __syncthreads();
    }

    const size_t ob = ((size_t)(b * NPIX + ipx)) * NPIX + j;
    out[ob] = acc0;
    out[ob + 8 * NPIX] = acc1;
    out[ob + 16 * NPIX] = acc2;
    out[ob + 24 * NPIX] = acc3;
}

extern "C" void kernel_launch(void* const* d_in, const int* in_sizes, int n_in,
                              void* d_out, int out_size, void* d_ws, size_t ws_size,
                              hipStream_t stream) {
    float* sinos = (float*)d_in[0];          // [16,720,1024] f32, filtered in-place
    const float* kr = (const float*)d_in[1]; // [513]
    const float* ki = (const float*)d_in[2]; // [513]
    float* out = (float*)d_out;              // [16,256,256] f32

    char* wsb = nullptr;
    if (ws_size >= (size_t)WS_NEEDED && d_ws != nullptr) {
        wsb = (char*)d_ws;
        precompute_kernel<<<364, 256, 0, stream>>>(wsb);
    }
    filter_fft_kernel<<<NB * PHI / 4, 256, 0, stream>>>(sinos, kr, ki, wsb);
    if (wsb) {
        hipMemsetAsync(d_out, 0, (size_t)out_size * sizeof(float), stream);
        backproj_sym_kernel<<<4096, 128, 0, stream>>>(sinos, out, wsb);
    } else {
        backproj_fb_kernel<<<NB * 64, 256, 0, stream>>>(sinos, out);
    }
}

// Round 9
// 251.906 us; speedup vs baseline: 1.4136x; 1.0525x over previous
//
#include <hip/hip_runtime.h>

#define PHI 720
#define TS 1024
#define NB 16
#define NPIX 256

#define INVDT 362.03867196751236f      // 1024 / (2*sqrt(2))
#define DXF 0.0078125f                 // 2/256
#define DPHI_F 0.0043633231299858237f  // pi/720

// d_ws layout (bytes):
//   WS_TW : float2 tw[512]        FFT twiddles exp(-2pi i k/1024)
//   WS_ANG: float2 ang[360]       (cos*INVDT, sin*INVDT) for pair angle phi
//   WS_PT : uint4 [256][360]      per (rep-tile, angle-pair):
//           {bits(511.5-wbA), bits(511.5-wbC), wbA|wbB<<16, wbC|wbD<<16}
#define WS_TW 0
#define WS_ANG 4096
#define WS_PT 8192
#define WS_NEEDED (8192 + 256 * 360 * 16)

// LDS swizzle for the FFT buffers: spreads the Stockham scatter-writes
// (stride 4/16/64 float2) across bank-pairs. Bijective (17g+r form) for i<1024.
#define FSW(i) ((i) + ((i) >> 4))

__device__ __forceinline__ float2 cmulf2(float2 a, float2 b) {
    return make_float2(a.x * b.x - a.y * b.y, a.x * b.y + a.y * b.x);
}
__device__ __forceinline__ float fract_fast(float x) {
#if __has_builtin(__builtin_amdgcn_fractf)
    return __builtin_amdgcn_fractf(x);
#else
    return x - floorf(x);
#endif
}

// ---------------------------------------------------------------------------
// Kernel 0: tables into d_ws (recomputed every launch; graph-safe).
// (verified R4/R7)
// ---------------------------------------------------------------------------
__global__ __launch_bounds__(256) void precompute_kernel(char* __restrict__ wsb) {
    const int blk = blockIdx.x, tid = threadIdx.x;
    if (blk < 360) {
        const int e = blk * 256 + tid;                 // 92160 entries
        const unsigned repu = (unsigned)e / 360u;
        const int rep = (int)repu;
        const int a = e - rep * 360;
        const int ti = rep >> 4, tj = rep & 15;
        float s, c;
        sincosf(((float)a + 0.5f) * (3.14159265358979323846f / 720.0f), &s, &c);
        const float x0 = -1.0f + ((float)(ti * 8) + 0.5f) * DXF;
        const float x7 = x0 + 7.0f * DXF;
        const float y0 = -1.0f + ((float)(tj * 8) + 0.5f) * DXF;
        const float y7 = y0 + 7.0f * DXF;
        const float uTmin = (c * x0 + s * y0) * INVDT + 511.5f;
        const float uTmax = (c * x7 + s * y7) * INVDT + 511.5f;
        const float uUmin = (s * x0 - c * y7) * INVDT + 511.5f;
        const float uUmax = (s * x7 - c * y0) * INVDT + 511.5f;
        int wbA = (int)floorf(uTmin - 0.02f) - 1;                 // +T window
        int wbB = (int)floorf(1023.0f - uTmax - 0.02f) - 1;       // -T window
        int wbC = (int)floorf(uUmin - 0.02f) - 1;                 // +U window
        int wbD = (int)floorf(1023.0f - uUmax - 0.02f) - 1;       // -U window
        wbA = min(max(wbA, 0), 992);
        wbB = min(max(wbB, 0), 992);
        wbC = min(max(wbC, 0), 992);
        wbD = min(max(wbD, 0), 992);
        uint4 ent;
        ent.x = __float_as_uint(511.5f - (float)wbA);
        ent.y = __float_as_uint(511.5f - (float)wbC);
        ent.z = (unsigned)wbA | ((unsigned)wbB << 16);
        ent.w = (unsigned)wbC | ((unsigned)wbD << 16);
        ((uint4*)(wsb + WS_PT))[e] = ent;
    } else if (blk < 362) {
        const int k = (blk - 360) * 256 + tid;
        float s, c;
        sincosf((float)k * (6.28318530717958647692f / 1024.0f), &s, &c);
        ((float2*)(wsb + WS_TW))[k] = make_float2(c, -s);
    } else {
        const int a = (blk - 362) * 256 + tid;
        if (a < 360) {
            float s, c;
            sincosf(((float)a + 0.5f) * (3.14159265358979323846f / 720.0f), &s, &c);
            ((float2*)(wsb + WS_ANG))[a] = make_float2(c * INVDT, s * INVDT);
        }
    }
}

// ---------------------------------------------------------------------------
// Kernel 1: circular filtering row <- irfft(K * rfft(row)) * DPHI.
// Radix-4 Stockham (math verified R3-R7). R8/R9:
//  - FSW swizzle on all data-buffer LDS accesses;
//  - first fwd stage fused with global load, last inv stage fused with store;
//  - K-multiply fused into first inverse stage. 9 barriers.
// ---------------------------------------------------------------------------
__device__ __forceinline__ void r4_sw(const float2* __restrict__ s0, float2* __restrict__ d0,
                                      const float2* __restrict__ s1, float2* __restrict__ d1,
                                      const float2* __restrict__ tw, int tid, int m, bool inv) {
    const int q = tid & ~(m - 1);
    const int o = tid + 3 * q;
    float2 w1 = tw[q], w2 = tw[2 * q];
    if (inv) { w1.y = -w1.y; w2.y = -w2.y; }
    #pragma unroll
    for (int f = 0; f < 2; ++f) {
        const float2* s = f ? s1 : s0;
        float2* d = f ? d1 : d0;
        const float2 a = s[FSW(tid)], b = s[FSW(tid + 256)];
        const float2 c = s[FSW(tid + 512)], e = s[FSW(tid + 768)];
        const float2 A = make_float2(a.x + c.x, a.y + c.y);
        const float2 Bm = cmulf2(w1, make_float2(a.x - c.x, a.y - c.y));
        const float2 C = make_float2(b.x + e.x, b.y + e.y);
        const float2 Dm = cmulf2(w1, make_float2(b.x - e.x, b.y - e.y));
        const float2 D = inv ? make_float2(-Dm.y, Dm.x) : make_float2(Dm.y, -Dm.x);
        d[FSW(o)]         = make_float2(A.x + C.x, A.y + C.y);
        d[FSW(o + m)]     = make_float2(Bm.x + D.x, Bm.y + D.y);
        d[FSW(o + 2 * m)] = cmulf2(w2, make_float2(A.x - C.x, A.y - C.y));
        d[FSW(o + 3 * m)] = cmulf2(w2, make_float2(Bm.x - D.x, Bm.y - D.y));
    }
}

__device__ __forceinline__ float2 kfac(const float* __restrict__ kr,
                                       const float* __restrict__ ki, int k, float scale) {
    const int kk = (k <= 512) ? k : (1024 - k);
    const float re = kr[kk] * scale;
    float im = ((k == 0) || (k == 512)) ? 0.0f : ki[kk] * scale;
    if (k > 512) im = -im;
    return make_float2(re, im);
}

__global__ __launch_bounds__(256) void filter_fft_kernel(float* __restrict__ sinos,
                                                         const float* __restrict__ kr,
                                                         const float* __restrict__ ki,
                                                         const char* __restrict__ wsb) {
    __shared__ float2 bufA[2][1088];     // 1024 + 64 swizzle pad
    __shared__ float2 bufB[2][1088];
    __shared__ float2 tw[512];
    const int tid = threadIdx.x;
    const int wg = blockIdx.x;
    const int lb = (wg & 7) * 360 + (wg >> 3);
    float* base = sinos + (size_t)lb * 4096;

    // twiddles: LDS table for middle stages + registers for the fused stage 1
    float2 w1f, w2f;
    if (wsb) {
        const float2* tg = (const float2*)(wsb + WS_TW);
        tw[tid] = tg[tid];
        tw[tid + 256] = tg[tid + 256];
        w1f = tg[tid];
        w2f = tg[2 * tid];
    } else {
        #pragma unroll
        for (int h = 0; h < 2; ++h) {
            const int k = tid + h * 256;
            float s, c;
            sincosf((float)k * (6.28318530717958647692f / 1024.0f), &s, &c);
            tw[k] = make_float2(c, -s);
        }
        float s, c;
        sincosf((float)tid * (6.28318530717958647692f / 1024.0f), &s, &c);
        w1f = make_float2(c, -s);
        sincosf((float)(2 * tid) * (6.28318530717958647692f / 1024.0f), &s, &c);
        w2f = make_float2(c, -s);
    }

    // fused: global load -> fwd stage m=1 (q=tid) -> scatter into bufA
    #pragma unroll
    for (int f = 0; f < 2; ++f) {
        const float* r0 = base + f * 2048;
        const float* r1 = r0 + 1024;
        const float2 a = make_float2(r0[tid], r1[tid]);
        const float2 b = make_float2(r0[tid + 256], r1[tid + 256]);
        const float2 c = make_float2(r0[tid + 512], r1[tid + 512]);
        const float2 e = make_float2(r0[tid + 768], r1[tid + 768]);
        const float2 A = make_float2(a.x + c.x, a.y + c.y);
        const float2 Bm = cmulf2(w1f, make_float2(a.x - c.x, a.y - c.y));
        const float2 C = make_float2(b.x + e.x, b.y + e.y);
        const float2 Dm = cmulf2(w1f, make_float2(b.x - e.x, b.y - e.y));
        const float2 D = make_float2(Dm.y, -Dm.x);
        const int o = 4 * tid;
        bufA[f][FSW(o)]     = make_float2(A.x + C.x, A.y + C.y);
        bufA[f][FSW(o + 1)] = make_float2(Bm.x + D.x, Bm.y + D.y);
        bufA[f][FSW(o + 2)] = cmulf2(w2f, make_float2(A.x - C.x, A.y - C.y));
        bufA[f][FSW(o + 3)] = cmulf2(w2f, make_float2(Bm.x - D.x, Bm.y - D.y));
    }
    __syncthreads();

    r4_sw(bufA[0], bufB[0], bufA[1], bufB[1], tw, tid, 4, false);   __syncthreads();
    r4_sw(bufB[0], bufA[0], bufB[1], bufA[1], tw, tid, 16, false);  __syncthreads();
    r4_sw(bufA[0], bufB[0], bufA[1], bufB[1], tw, tid, 64, false);  __syncthreads();
    r4_sw(bufB[0], bufA[0], bufB[1], bufA[1], tw, tid, 256, false); __syncthreads();

    // fused: K-multiply + first inverse stage (m=1): bufA -> bufB
    {
        const float scale = DPHI_F / 1024.0f;
        const int o = 4 * tid;
        float2 w1 = tw[tid], w2 = tw[2 * tid];
        w1.y = -w1.y; w2.y = -w2.y;
        const float2 f0 = kfac(kr, ki, tid, scale);
        const float2 f1 = kfac(kr, ki, tid + 256, scale);
        const float2 f2 = kfac(kr, ki, tid + 512, scale);
        const float2 f3 = kfac(kr, ki, tid + 768, scale);
        #pragma unroll
        for (int f = 0; f < 2; ++f) {
            const float2* s = bufA[f];
            float2* d = bufB[f];
            const float2 a = cmulf2(f0, s[FSW(tid)]);
            const float2 b = cmulf2(f1, s[FSW(tid + 256)]);
            const float2 c = cmulf2(f2, s[FSW(tid + 512)]);
            const float2 e = cmulf2(f3, s[FSW(tid + 768)]);
            const float2 A = make_float2(a.x + c.x, a.y + c.y);
            const float2 Bm = cmulf2(w1, make_float2(a.x - c.x, a.y - c.y));
            const float2 C = make_float2(b.x + e.x, b.y + e.y);
            const float2 Dm = cmulf2(w1, make_float2(b.x - e.x, b.y - e.y));
            const float2 D = make_float2(-Dm.y, Dm.x);
            d[FSW(o)]     = make_float2(A.x + C.x, A.y + C.y);
            d[FSW(o + 1)] = make_float2(Bm.x + D.x, Bm.y + D.y);
            d[FSW(o + 2)] = cmulf2(w2, make_float2(A.x - C.x, A.y - C.y));
            d[FSW(o + 3)] = cmulf2(w2, make_float2(Bm.x - D.x, Bm.y - D.y));
        }
    }
    __syncthreads();

    r4_sw(bufB[0], bufA[0], bufB[1], bufA[1], tw, tid, 4, true);   __syncthreads();
    r4_sw(bufA[0], bufB[0], bufA[1], bufB[1], tw, tid, 16, true);  __syncthreads();
    r4_sw(bufB[0], bufA[0], bufB[1], bufA[1], tw, tid, 64, true);  __syncthreads();

    // fused: final inverse stage (m=256, q=0 => unit twiddles) -> global store
    #pragma unroll
    for (int f = 0; f < 2; ++f) {
        const float2* s = bufA[f];
        float* r0 = base + f * 2048;
        float* r1 = r0 + 1024;
        const float2 a = s[FSW(tid)], b = s[FSW(tid + 256)];
        const float2 c = s[FSW(tid + 512)], e = s[FSW(tid + 768)];
        const float2 A = make_float2(a.x + c.x, a.y + c.y);
        const float2 Bm = make_float2(a.x - c.x, a.y - c.y);
        const float2 C = make_float2(b.x + e.x, b.y + e.y);
        const float2 Dm = make_float2(b.x - e.x, b.y - e.y);
        const float2 D = make_float2(-Dm.y, Dm.x);
        r0[tid]       = A.x + C.x;  r1[tid]       = A.y + C.y;
        r0[tid + 256] = Bm.x + D.x; r1[tid + 256] = Bm.y + D.y;
        r0[tid + 512] = A.x - C.x;  r1[tid + 512] = A.y - C.y;
        r0[tid + 768] = Bm.x - D.x; r1[tid + 768] = Bm.y - D.y;
    }
}

// ---------------------------------------------------------------------------
// Kernel 2 (fast path): 4-fold-symmetric backprojection, 2 independent waves
// per block (angle-split, private LDS halves, zero barriers in the loop).
// R9 fix: combine area moved to DISJOINT lds[2048..2303] (R8 aliased wave 0's
// window buffer -> race). Wave 1 deposits, one barrier, wave 0 adds+stores.
// Index math identical to verified R4/R7 kernels.
// ---------------------------------------------------------------------------
__global__ __launch_bounds__(128, 8) void backproj_sym_kernel(const float* __restrict__ filt,
                                                              float* __restrict__ out,
                                                              const char* __restrict__ wsb) {
    __shared__ float lds[2304];      // [wave:2][buf:2][pair:2][256] + combine[256]
    const int tid = threadIdx.x;
    const int hf = __builtin_amdgcn_readfirstlane(tid >> 6);  // wave id, scalar
    const int l = tid & 63;
    // XCD swizzle: 4096 blocks -> each XCD owns 512 logical blocks = 2 batches.
    const int wg = blockIdx.x;
    const int lb = ((wg & 7) << 9) | (wg >> 3);
    const int b = lb >> 8;
    const int rep = lb & 255;
    const int ti = rep >> 4, tj = rep & 15;

    const float2* __restrict__ ang = (const float2*)(wsb + WS_ANG);
    const uint4* __restrict__ pt = ((const uint4*)(wsb + WS_PT)) + rep * 360;

    const int ii = l >> 3, jj = l & 7;
    const int ip = ti * 8 + ii, jp = tj * 8 + jj;
    const float Xc = -1.0f + ((float)ip + 0.5f) * DXF;
    const float Yc = -1.0f + ((float)jp + 0.5f) * DXF;
    // static per-lane byte offset: lanes 0-31 phi-row[k], 32-63 theta-row[k]
    const int vbyte = ((l & 31) + ((l >> 5) * (360 * 1024))) * 4;
    const float* __restrict__ gb = filt + (size_t)b * (PHI * TS);
    const int lbase = hf * 1024;

    float aP[2][4] = {{0.f, 0.f, 0.f, 0.f}, {0.f, 0.f, 0.f, 0.f}};
    float pf[2][4];

#define STAGE(CH) { \
    _Pragma("unroll") \
    for (int p = 0; p < 2; ++p) { \
        const int ap = hf * 180 + (CH) * 2 + p; \
        const uint4 e = pt[ap]; \
        const char* rp = (const char*)(gb + (ap << 10)); \
        pf[p][0] = *(const float*)(rp + ((e.z & 0xFFFFu) << 2) + vbyte); \
        pf[p][1] = *(const float*)(rp + ((e.z >> 16) << 2) + vbyte); \
        pf[p][2] = *(const float*)(rp + ((e.w & 0xFFFFu) << 2) + vbyte); \
        pf[p][3] = *(const float*)(rp + ((e.w >> 16) << 2) + vbyte); \
    } }

#define WRITE(BUF) { \
    _Pragma("unroll") \
    for (int p = 0; p < 2; ++p) { \
        _Pragma("unroll") \
        for (int w = 0; w < 4; ++w) \
            lds[lbase + (BUF) * 512 + p * 256 + w * 64 + l] = pf[p][w]; \
    } }

#define COMPUTE(BUF, CH) { \
    _Pragma("unroll") \
    for (int p = 0; p < 2; ++p) { \
        const int ap = hf * 180 + (CH) * 2 + p; \
        const uint4 e = pt[ap]; \
        const float2 cs = ang[ap]; \
        const float* slot = &lds[lbase + (BUF) * 512 + p * 256]; \
        const float kFA = __uint_as_float(e.x), kFC = __uint_as_float(e.y); \
        const int wbA = (int)(e.z & 0xFFFFu), wbB = (int)(e.z >> 16); \
        const int wbC = (int)(e.w & 0xFFFFu), wbD = (int)(e.w >> 16); \
        const float uT = fmaf(cs.x, Xc, fmaf(cs.y, Yc, kFA)); \
        const float uU = fmaf(cs.y, Xc, fmaf(cs.x, -Yc, kFC)); \
        const int iA = (int)uT; const float wT = fract_fast(uT); const float oT = 1.0f - wT; \
        const int iC = (int)uU; const float wU = fract_fast(uU); const float oU = 1.0f - wU; \
        const int iB = 1022 - wbA - wbB - iA; \
        const int iD = 1022 - wbC - wbD - iC; \
        { const float g0 = slot[iA],       g1 = slot[iA + 1]; \
          const float h0 = slot[iA + 32],  h1 = slot[iA + 33]; \
          aP[p][0] = fmaf(g0, oT, aP[p][0]); aP[p][0] = fmaf(g1, wT, aP[p][0]); \
          aP[p][1] = fmaf(h0, oT, aP[p][1]); aP[p][1] = fmaf(h1, wT, aP[p][1]); } \
        { const float g0 = slot[64 + iB],  g1 = slot[65 + iB]; \
          const float h0 = slot[96 + iB],  h1 = slot[97 + iB]; \
          aP[p][2] = fmaf(g1, oT, aP[p][2]); aP[p][2] = fmaf(g0, wT, aP[p][2]); \
          aP[p][3] = fmaf(h1, oT, aP[p][3]); aP[p][3] = fmaf(h0, wT, aP[p][3]); } \
        { const float g0 = slot[128 + iC], g1 = slot[129 + iC]; \
          const float h0 = slot[160 + iC], h1 = slot[161 + iC]; \
          aP[p][1] = fmaf(g0, oU, aP[p][1]); aP[p][1] = fmaf(g1, wU, aP[p][1]); \
          aP[p][2] = fmaf(h0, oU, aP[p][2]); aP[p][2] = fmaf(h1, wU, aP[p][2]); } \
        { const float g0 = slot[192 + iD], g1 = slot[193 + iD]; \
          const float h0 = slot[224 + iD], h1 = slot[225 + iD]; \
          aP[p][3] = fmaf(g1, oU, aP[p][3]); aP[p][3] = fmaf(g0, wU, aP[p][3]); \
          aP[p][0] = fmaf(h1, oU, aP[p][0]); aP[p][0] = fmaf(h0, wU, aP[p][0]); } \
    } }

    STAGE(0); WRITE(0);
    for (int cc = 0; cc < 44; ++cc) {
        STAGE(2 * cc + 1);
        COMPUTE(0, 2 * cc);
        WRITE(1);
        STAGE(2 * cc + 2);
        COMPUTE(1, 2 * cc + 1);
        WRITE(0);
    }
    STAGE(89);
    COMPUTE(0, 88);
    WRITE(1);
    COMPUTE(1, 89);

#undef STAGE
#undef WRITE
#undef COMPUTE

    // cross-wave combine in DISJOINT LDS region (no aliasing with windows)
    const float s0 = aP[0][0] + aP[1][0];
    const float s1 = aP[0][1] + aP[1][1];
    const float s2 = aP[0][2] + aP[1][2];
    const float s3 = aP[0][3] + aP[1][3];
    if (hf == 1) {
        lds[2048 + (l << 2) + 0] = s0;
        lds[2048 + (l << 2) + 1] = s1;
        lds[2048 + (l << 2) + 2] = s2;
        lds[2048 + (l << 2) + 3] = s3;
    }
    __syncthreads();
    if (hf == 0) {
        const int bb = b << 8;
        out[((size_t)((bb + ip) << 8)) + jp]               = s0 + lds[2048 + (l << 2) + 0];
        out[((size_t)((bb + 255 - jp) << 8)) + ip]         = s1 + lds[2048 + (l << 2) + 1];
        out[((size_t)((bb + 255 - ip) << 8)) + (255 - jp)] = s2 + lds[2048 + (l << 2) + 2];
        out[((size_t)((bb + jp) << 8)) + (255 - ip)]       = s3 + lds[2048 + (l << 2) + 3];
    }
}

// ---------------------------------------------------------------------------
// Fallback backprojection (ws too small): R2's verified 256-thread kernel.
// ---------------------------------------------------------------------------
__global__ __launch_bounds__(256) void backproj_fb_kernel(const float* __restrict__ filt,
                                                          float* __restrict__ out) {
    __shared__ float2 csI[PHI];
    __shared__ float win[8 * 128];
    __shared__ float woffF[8];

    const int tid = threadIdx.x;
    const int wg = blockIdx.x;
    const int lb = ((wg & 7) << 7) | (wg >> 3);
    const int b = lb >> 6;
    const int tile = lb & 63;
    const int i0 = (tile >> 3) * 32;
    const int j0 = (tile & 7) * 32;

    for (int p = tid; p < PHI; p += 256) {
        const float angv = ((float)p + 0.5f) * (float)(3.14159265358979323846 / 720.0);
        float s, c;
        sincosf(angv, &s, &c);
        csI[p] = make_float2(c * INVDT, s * INVDT);
    }

    const int lane = tid & 63;
    const int wv = tid >> 6;
    const int ii = lane & 7;
    const int jj = lane >> 3;
    const int ipx = i0 + ii;
    const int j = j0 + wv * 8 + jj;

    const float Xc = -1.0f + ((float)ipx + 0.5f) * DXF;
    const float Yc = -1.0f + ((float)j + 0.5f) * DXF;

    const int r = tid >> 5;
    const int l32 = tid & 31;
    const float xlo = -1.0f + ((float)i0 + 0.5f) * DXF;
    const float xhi = -1.0f + ((float)i0 + 31.5f) * DXF;
    const float ylo = -1.0f + ((float)j0 + 0.5f) * DXF;
    const float yhi = -1.0f + ((float)j0 + 31.5f) * DXF;

    const float* gb = filt + (size_t)b * PHI * TS;
    float acc0 = 0.f, acc1 = 0.f, acc2 = 0.f, acc3 = 0.f;

    __syncthreads();

    {
        const float2 cs = csI[r];
        const float um = fminf(cs.x * xlo, cs.x * xhi) + fminf(cs.y * ylo, cs.y * yhi) + 511.5f;
        const int wb = (int)floorf(um) - 1;
        const float* grow = gb + (size_t)r * TS;
        #pragma unroll
        for (int h = 0; h < 4; ++h) {
            int gi = wb + l32 + 32 * h;
            gi = gi < 0 ? 0 : (gi > TS - 1 ? TS - 1 : gi);
            win[r * 128 + l32 + 32 * h] = grow[gi];
        }
        if (l32 == 0) woffF[r] = 511.5f + (float)(r * 128 - wb);
    }
    __syncthreads();

    for (int c = 0; c < PHI / 8; ++c) {
        float gp0 = 0.f, gp1 = 0.f, gp2 = 0.f, gp3 = 0.f;
        int wbn = 0;
        const bool more = (c + 1 < PHI / 8);
        if (more) {
            const int a = (c + 1) * 8 + r;
            const float2 cs = csI[a];
            const float um = fminf(cs.x * xlo, cs.x * xhi) + fminf(cs.y * ylo, cs.y * yhi) + 511.5f;
            wbn = (int)floorf(um) - 1;
            const float* grow = gb + (size_t)a * TS;
            int g0 = wbn + l32;      g0 = g0 < 0 ? 0 : (g0 > TS - 1 ? TS - 1 : g0);
            int g1 = wbn + l32 + 32; g1 = g1 < 0 ? 0 : (g1 > TS - 1 ? TS - 1 : g1);
            int g2 = wbn + l32 + 64; g2 = g2 < 0 ? 0 : (g2 > TS - 1 ? TS - 1 : g2);
            int g3 = wbn + l32 + 96; g3 = g3 < 0 ? 0 : (g3 > TS - 1 ? TS - 1 : g3);
            gp0 = grow[g0]; gp1 = grow[g1]; gp2 = grow[g2]; gp3 = grow[g3];
        }
        #pragma unroll
        for (int aa = 0; aa < 8; ++aa) {
            const float2 cs = csI[c * 8 + aa];
            const float offF = woffF[aa];
            float u = fmaf(cs.y, Yc, cs.x * Xc) + offF;
            const float dup = cs.x * 0.0625f;
            #pragma unroll
            for (int p = 0; p < 4; ++p) {
                const int idx = (int)u;
                const float wf = fract_fast(u);
                const float g0 = win[idx], g1 = win[idx + 1];
                if (p == 0) acc0 = fmaf(wf, g1 - g0, acc0 + g0);
                else if (p == 1) acc1 = fmaf(wf, g1 - g0, acc1 + g0);
                else if (p == 2) acc2 = fmaf(wf, g1 - g0, acc2 + g0);
                else acc3 = fmaf(wf, g1 - g0, acc3 + g0);
                u += dup;
            }
        }
        __syncthreads();
        if (more) {
            win[r * 128 + l32] = gp0;
            win[r * 128 + l32 + 32] = gp1;
            win[r * 128 + l32 + 64] = gp2;
            win[r * 128 + l32 + 96] = gp3;
            if (l32 == 0) woffF[r] = 511.5f + (float)(r * 128 - wbn);
        }
        __syncthreads();
    }

    const size_t ob = ((size_t)(b * NPIX + ipx)) * NPIX + j;
    out[ob] = acc0;
    out[ob + 8 * NPIX] = acc1;
    out[ob + 16 * NPIX] = acc2;
    out[ob + 24 * NPIX] = acc3;
}

extern "C" void kernel_launch(void* const* d_in, const int* in_sizes, int n_in,
                              void* d_out, int out_size, void* d_ws, size_t ws_size,
                              hipStream_t stream) {
    float* sinos = (float*)d_in[0];          // [16,720,1024] f32, filtered in-place
    const float* kr = (const float*)d_in[1]; // [513]
    const float* ki = (const float*)d_in[2]; // [513]
    float* out = (float*)d_out;              // [16,256,256] f32

    char* wsb = nullptr;
    if (ws_size >= (size_t)WS_NEEDED && d_ws != nullptr) {
        wsb = (char*)d_ws;
        precompute_kernel<<<364, 256, 0, stream>>>(wsb);
    }
    filter_fft_kernel<<<NB * PHI / 4, 256, 0, stream>>>(sinos, kr, ki, wsb);
    if (wsb) {
        backproj_sym_kernel<<<4096, 128, 0, stream>>>(sinos, out, wsb);
    } else {
        backproj_fb_kernel<<<NB * 64, 256, 0, stream>>>(sinos, out);
    }
}